// Round 2
// baseline (713.176 us; speedup 1.0000x reference)
//
#include <hip/hip_runtime.h>
#include <hip/hip_bf16.h>

#define B_SZ 4
#define CIN  256
#define CP   128
#define NN   4096
#define KSPLIT 4

// ---------------- wave reduction helpers (wave = 64 lanes) ----------------
__device__ __forceinline__ float wave_max64(float v){
  #pragma unroll
  for (int o = 32; o > 0; o >>= 1) v = fmaxf(v, __shfl_xor(v, o, 64));
  return v;
}
__device__ __forceinline__ float wave_sum64(float v){
  #pragma unroll
  for (int o = 32; o > 0; o >>= 1) v += __shfl_xor(v, o, 64);
  return v;
}

// ---------------- K1: t/p/g = W{t,p,g} @ x_b  (M=128 each, K=256, N=4096) ----
// blockIdx: x = n-tile (128), y = which matrix (0..2), z = batch
__global__ __launch_bounds__(256) void tpg_gemm(
    const float* __restrict__ Wt, const float* __restrict__ Wp,
    const float* __restrict__ Wg, const float* __restrict__ x,
    float* __restrict__ tq, float* __restrict__ pq, float* __restrict__ gq)
{
  const int b   = blockIdx.z;
  const int sel = blockIdx.y;
  const int n0  = blockIdx.x * 128;
  const float* W = (sel == 0) ? Wt : ((sel == 1) ? Wp : Wg);
  float* C = ((sel == 0) ? tq : ((sel == 1) ? pq : gq)) + (size_t)b * CP * NN;
  const float* xb = x + (size_t)b * CIN * NN;

  __shared__ float a_s[32][132];  // [k][c], padded stride for transpose stores
  __shared__ float b_s[32][128];  // [k][n]

  const int tid = threadIdx.x;
  const int tx = tid & 15, ty = tid >> 4;

  float acc[2][2][4][4];
  #pragma unroll
  for (int qa = 0; qa < 2; ++qa)
    #pragma unroll
    for (int qb = 0; qb < 2; ++qb)
      #pragma unroll
      for (int i = 0; i < 4; ++i)
        #pragma unroll
        for (int j = 0; j < 4; ++j) acc[qa][qb][i][j] = 0.f;

  for (int k0 = 0; k0 < CIN; k0 += 32){
    // A stage (transpose W[c][k] -> a_s[k][c]); 128x32 = 1024 float4 loads
    #pragma unroll
    for (int i = 0; i < 4; ++i){
      int f4i = tid + i * 256;
      int c  = f4i >> 3;
      int k4 = f4i & 7;
      float4 w = *(const float4*)(W + (size_t)c * CIN + k0 + k4 * 4);
      a_s[k4*4+0][c] = w.x;
      a_s[k4*4+1][c] = w.y;
      a_s[k4*4+2][c] = w.z;
      a_s[k4*4+3][c] = w.w;
    }
    // B stage (x rows, direct)
    #pragma unroll
    for (int i = 0; i < 4; ++i){
      int f4i = tid + i * 256;
      int kk = f4i >> 5;
      int n4 = f4i & 31;
      *(float4*)&b_s[kk][n4*4] =
          *(const float4*)(xb + (size_t)(k0 + kk) * NN + n0 + n4 * 4);
    }
    __syncthreads();
    #pragma unroll
    for (int kk = 0; kk < 32; ++kk){
      float af[8], bf[8];
      *(float4*)&af[0] = *(const float4*)&a_s[kk][ty*4];
      *(float4*)&af[4] = *(const float4*)&a_s[kk][ty*4+64];
      *(float4*)&bf[0] = *(const float4*)&b_s[kk][tx*4];
      *(float4*)&bf[4] = *(const float4*)&b_s[kk][tx*4+64];
      #pragma unroll
      for (int qa = 0; qa < 2; ++qa)
        #pragma unroll
        for (int i = 0; i < 4; ++i)
          #pragma unroll
          for (int qb = 0; qb < 2; ++qb)
            #pragma unroll
            for (int j = 0; j < 4; ++j)
              acc[qa][qb][i][j] = fmaf(af[qa*4+i], bf[qb*4+j], acc[qa][qb][i][j]);
    }
    __syncthreads();
  }
  #pragma unroll
  for (int qa = 0; qa < 2; ++qa)
    #pragma unroll
    for (int i = 0; i < 4; ++i){
      const int row = qa*64 + ty*4 + i;
      #pragma unroll
      for (int qb = 0; qb < 2; ++qb){
        float4 v = make_float4(acc[qa][qb][i][0], acc[qa][qb][i][1],
                               acc[qa][qb][i][2], acc[qa][qb][i][3]);
        *(float4*)(C + (size_t)row * NN + n0 + qb*64 + tx*4) = v;
      }
    }
}

// ---------------- K2: S[m][n] = sum_c p[c][m] * t[c][n]  (per batch) --------
// blockIdx: x = n-tile(128), y = m-tile(128), z = batch slot
__global__ __launch_bounds__(256) void s_gemm(
    const float* __restrict__ pq, const float* __restrict__ tq,
    float* __restrict__ S, int b0)
{
  const int b  = b0 + blockIdx.z;
  const int m0 = blockIdx.y * 128;
  const int n0 = blockIdx.x * 128;
  const float* pb = pq + (size_t)b * CP * NN;
  const float* tb = tq + (size_t)b * CP * NN;
  float* Sb = S + (size_t)blockIdx.z * NN * NN;

  __shared__ float a_s[32][128];  // [c][m] (direct rows of p)
  __shared__ float b_s[32][128];  // [c][n]

  const int tid = threadIdx.x;
  const int tx = tid & 15, ty = tid >> 4;

  float acc[2][2][4][4];
  #pragma unroll
  for (int qa = 0; qa < 2; ++qa)
    #pragma unroll
    for (int qb = 0; qb < 2; ++qb)
      #pragma unroll
      for (int i = 0; i < 4; ++i)
        #pragma unroll
        for (int j = 0; j < 4; ++j) acc[qa][qb][i][j] = 0.f;

  for (int k0 = 0; k0 < CP; k0 += 32){
    #pragma unroll
    for (int i = 0; i < 4; ++i){
      int f4i = tid + i * 256;
      int kk = f4i >> 5;
      int m4 = f4i & 31;
      *(float4*)&a_s[kk][m4*4] =
          *(const float4*)(pb + (size_t)(k0 + kk) * NN + m0 + m4 * 4);
      *(float4*)&b_s[kk][m4*4] =
          *(const float4*)(tb + (size_t)(k0 + kk) * NN + n0 + m4 * 4);
    }
    __syncthreads();
    #pragma unroll
    for (int kk = 0; kk < 32; ++kk){
      float af[8], bf[8];
      *(float4*)&af[0] = *(const float4*)&a_s[kk][ty*4];
      *(float4*)&af[4] = *(const float4*)&a_s[kk][ty*4+64];
      *(float4*)&bf[0] = *(const float4*)&b_s[kk][tx*4];
      *(float4*)&bf[4] = *(const float4*)&b_s[kk][tx*4+64];
      #pragma unroll
      for (int qa = 0; qa < 2; ++qa)
        #pragma unroll
        for (int i = 0; i < 4; ++i)
          #pragma unroll
          for (int qb = 0; qb < 2; ++qb)
            #pragma unroll
            for (int j = 0; j < 4; ++j)
              acc[qa][qb][i][j] = fmaf(af[qa*4+i], bf[qb*4+j], acc[qa][qb][i][j]);
    }
    __syncthreads();
  }
  #pragma unroll
  for (int qa = 0; qa < 2; ++qa)
    #pragma unroll
    for (int i = 0; i < 4; ++i){
      const int row = m0 + qa*64 + ty*4 + i;
      #pragma unroll
      for (int qb = 0; qb < 2; ++qb){
        float4 v = make_float4(acc[qa][qb][i][0], acc[qa][qb][i][1],
                               acc[qa][qb][i][2], acc[qa][qb][i][3]);
        *(float4*)(Sb + (size_t)row * NN + n0 + qb*64 + tx*4) = v;
      }
    }
}

// ---------------- K3: per-row (m) max and 1/sum(exp) of S ------------------
// blockIdx: x = m (4096), z = batch slot
__global__ __launch_bounds__(256) void row_stats(
    const float* __restrict__ S, float* __restrict__ rowmax,
    float* __restrict__ rowrls, int b0)
{
  const int m  = blockIdx.x;
  const int bz = blockIdx.z;
  const float4* row = (const float4*)(S + ((size_t)bz * NN + m) * NN);
  const int tid = threadIdx.x;
  float4 v[4];
  float mx = -3.0e38f;
  #pragma unroll
  for (int i = 0; i < 4; ++i){
    v[i] = row[tid + i*256];
    mx = fmaxf(mx, fmaxf(fmaxf(v[i].x, v[i].y), fmaxf(v[i].z, v[i].w)));
  }
  __shared__ float redm[4];
  __shared__ float reds[4];
  mx = wave_max64(mx);
  const int wid = tid >> 6, lane = tid & 63;
  if (lane == 0) redm[wid] = mx;
  __syncthreads();
  mx = fmaxf(fmaxf(redm[0], redm[1]), fmaxf(redm[2], redm[3]));
  float s = 0.f;
  #pragma unroll
  for (int i = 0; i < 4; ++i)
    s += __expf(v[i].x - mx) + __expf(v[i].y - mx)
       + __expf(v[i].z - mx) + __expf(v[i].w - mx);
  s = wave_sum64(s);
  if (lane == 0) reds[wid] = s;
  __syncthreads();
  if (tid == 0){
    const int idx = (b0 + bz) * NN + m;
    rowmax[idx] = mx;
    rowrls[idx] = 1.f / (reds[0] + reds[1] + reds[2] + reds[3]);
  }
}

// ---------------- K4: y[c][n] = sum_m (g[c][m]/l_m) * exp(S[m][n]-max_m) ----
// blockIdx: x = n-tile(64), y = K-split chunk, z = batch slot
__global__ __launch_bounds__(256) void y_gemm(
    const float* __restrict__ gq, const float* __restrict__ S,
    const float* __restrict__ rowmax, const float* __restrict__ rowrls,
    float* __restrict__ y, int b0)
{
  const int b  = b0 + blockIdx.z;
  const int kh = blockIdx.y;
  const int n0 = blockIdx.x * 64;
  const float* gb  = gq + (size_t)b * CP * NN;
  const float* Sb  = S + (size_t)blockIdx.z * NN * NN;
  const float* rmb = rowmax + (size_t)b * NN;
  const float* rlb = rowrls + (size_t)b * NN;
  float* yb = y + ((size_t)kh * B_SZ + b) * CP * NN;

  __shared__ float a_s[32][132];  // [m][c] of g' (transposed, padded)
  __shared__ float b_s[32][64];   // [m][n] of E (exp applied in staging)

  const int tid = threadIdx.x;
  const int tx = tid & 15, ty = tid >> 4;

  float acc[2][4][4];
  #pragma unroll
  for (int qa = 0; qa < 2; ++qa)
    #pragma unroll
    for (int i = 0; i < 4; ++i)
      #pragma unroll
      for (int j = 0; j < 4; ++j) acc[qa][i][j] = 0.f;

  const int kbeg = kh * (NN / KSPLIT);
  const int kend = kbeg + (NN / KSPLIT);
  for (int k0 = kbeg; k0 < kend; k0 += 32){
    // A stage: transpose g[c][m] -> a_s[m][c], fold in 1/l_m
    #pragma unroll
    for (int i = 0; i < 4; ++i){
      int f4i = tid + i * 256;
      int c  = f4i >> 3;
      int k4 = f4i & 7;
      float4 w = *(const float4*)(gb + (size_t)c * NN + k0 + k4 * 4);
      float4 r = *(const float4*)(rlb + k0 + k4 * 4);
      a_s[k4*4+0][c] = w.x * r.x;
      a_s[k4*4+1][c] = w.y * r.y;
      a_s[k4*4+2][c] = w.z * r.z;
      a_s[k4*4+3][c] = w.w * r.w;
    }
    // B stage: E = exp(S - rowmax), each S element exp'd exactly once
    #pragma unroll
    for (int i = 0; i < 2; ++i){
      int f4i = tid + i * 256;
      int kk = f4i >> 4;
      int n4 = f4i & 15;
      float4 s4 = *(const float4*)(Sb + (size_t)(k0 + kk) * NN + n0 + n4 * 4);
      const float mx = rmb[k0 + kk];
      float4 e;
      e.x = __expf(s4.x - mx);
      e.y = __expf(s4.y - mx);
      e.z = __expf(s4.z - mx);
      e.w = __expf(s4.w - mx);
      *(float4*)&b_s[kk][n4*4] = e;
    }
    __syncthreads();
    #pragma unroll
    for (int kk = 0; kk < 32; ++kk){
      float af[8], bf[4];
      *(float4*)&af[0] = *(const float4*)&a_s[kk][ty*4];
      *(float4*)&af[4] = *(const float4*)&a_s[kk][ty*4+64];
      *(float4*)&bf[0] = *(const float4*)&b_s[kk][tx*4];
      #pragma unroll
      for (int qa = 0; qa < 2; ++qa)
        #pragma unroll
        for (int i = 0; i < 4; ++i)
          #pragma unroll
          for (int j = 0; j < 4; ++j)
            acc[qa][i][j] = fmaf(af[qa*4+i], bf[j], acc[qa][i][j]);
    }
    __syncthreads();
  }
  #pragma unroll
  for (int qa = 0; qa < 2; ++qa)
    #pragma unroll
    for (int i = 0; i < 4; ++i){
      const int row = qa*64 + ty*4 + i;
      float4 v = make_float4(acc[qa][i][0], acc[qa][i][1],
                             acc[qa][i][2], acc[qa][i][3]);
      *(float4*)(yb + (size_t)row * NN + n0 + tx*4) = v;
    }
}

// ---------------- K5: z = Wz @ y (sums the 4 K-split partials) --------------
// blockIdx: x = n-tile(64), y = o-tile(128 of 256), z = batch
__global__ __launch_bounds__(256) void z_gemm(
    const float* __restrict__ Wz, const float* __restrict__ y,
    float* __restrict__ z)
{
  const int b  = blockIdx.z;
  const int o0 = blockIdx.y * 128;
  const int n0 = blockIdx.x * 64;
  const float* y0 = y + ((size_t)0 * B_SZ + b) * CP * NN;
  const float* y1 = y + ((size_t)1 * B_SZ + b) * CP * NN;
  const float* y2 = y + ((size_t)2 * B_SZ + b) * CP * NN;
  const float* y3 = y + ((size_t)3 * B_SZ + b) * CP * NN;
  float* zb = z + (size_t)b * CIN * NN;

  __shared__ float a_s[32][132];  // [k][o] of Wz (transposed)
  __shared__ float b_s[32][64];   // [k][n] of y (partials summed)

  const int tid = threadIdx.x;
  const int tx = tid & 15, ty = tid >> 4;

  float acc[2][4][4];
  #pragma unroll
  for (int qa = 0; qa < 2; ++qa)
    #pragma unroll
    for (int i = 0; i < 4; ++i)
      #pragma unroll
      for (int j = 0; j < 4; ++j) acc[qa][i][j] = 0.f;

  for (int k0 = 0; k0 < CP; k0 += 32){
    #pragma unroll
    for (int i = 0; i < 4; ++i){
      int f4i = tid + i * 256;
      int c  = f4i >> 3;
      int k4 = f4i & 7;
      float4 w = *(const float4*)(Wz + (size_t)(o0 + c) * CP + k0 + k4 * 4);
      a_s[k4*4+0][c] = w.x;
      a_s[k4*4+1][c] = w.y;
      a_s[k4*4+2][c] = w.z;
      a_s[k4*4+3][c] = w.w;
    }
    #pragma unroll
    for (int i = 0; i < 2; ++i){
      int f4i = tid + i * 256;
      int kk = f4i >> 4;
      int n4 = f4i & 15;
      const size_t off = (size_t)(k0 + kk) * NN + n0 + n4 * 4;
      float4 v0 = *(const float4*)(y0 + off);
      float4 v1 = *(const float4*)(y1 + off);
      float4 v2 = *(const float4*)(y2 + off);
      float4 v3 = *(const float4*)(y3 + off);
      float4 sv;
      sv.x = v0.x + v1.x + v2.x + v3.x;
      sv.y = v0.y + v1.y + v2.y + v3.y;
      sv.z = v0.z + v1.z + v2.z + v3.z;
      sv.w = v0.w + v1.w + v2.w + v3.w;
      *(float4*)&b_s[kk][n4*4] = sv;
    }
    __syncthreads();
    #pragma unroll
    for (int kk = 0; kk < 32; ++kk){
      float af[8], bf[4];
      *(float4*)&af[0] = *(const float4*)&a_s[kk][ty*4];
      *(float4*)&af[4] = *(const float4*)&a_s[kk][ty*4+64];
      *(float4*)&bf[0] = *(const float4*)&b_s[kk][tx*4];
      #pragma unroll
      for (int qa = 0; qa < 2; ++qa)
        #pragma unroll
        for (int i = 0; i < 4; ++i)
          #pragma unroll
          for (int j = 0; j < 4; ++j)
            acc[qa][i][j] = fmaf(af[qa*4+i], bf[j], acc[qa][i][j]);
    }
    __syncthreads();
  }
  #pragma unroll
  for (int qa = 0; qa < 2; ++qa)
    #pragma unroll
    for (int i = 0; i < 4; ++i){
      const int row = o0 + qa*64 + ty*4 + i;
      float4 v = make_float4(acc[qa][i][0], acc[qa][i][1],
                             acc[qa][i][2], acc[qa][i][3]);
      *(float4*)(zb + (size_t)row * NN + n0 + tx*4) = v;
    }
}

// ---------------- K6: BatchNorm batch stats per channel ---------------------
__global__ __launch_bounds__(256) void bn_stats(
    const float* __restrict__ z, float* __restrict__ mean,
    float* __restrict__ rstd)
{
  const int c = blockIdx.x;
  const int tid = threadIdx.x;
  float s = 0.f, s2 = 0.f;
  for (int b = 0; b < B_SZ; ++b){
    const float4* row = (const float4*)(z + ((size_t)b * CIN + c) * NN);
    #pragma unroll
    for (int i = 0; i < 4; ++i){
      float4 v = row[tid + i*256];
      s  += v.x + v.y + v.z + v.w;
      s2 += v.x*v.x + v.y*v.y + v.z*v.z + v.w*v.w;
    }
  }
  s  = wave_sum64(s);
  s2 = wave_sum64(s2);
  __shared__ float rs[4];
  __shared__ float rq[4];
  const int wid = tid >> 6, lane = tid & 63;
  if (lane == 0){ rs[wid] = s; rq[wid] = s2; }
  __syncthreads();
  if (tid == 0){
    const float S1 = rs[0]+rs[1]+rs[2]+rs[3];
    const float S2 = rq[0]+rq[1]+rq[2]+rq[3];
    const float inv = 1.f / (float)(B_SZ * NN);
    const float m = S1 * inv;
    const float var = S2 * inv - m * m;
    mean[c] = m;
    rstd[c] = 1.f / sqrtf(var + 1e-5f);
  }
}

// ---------------- K7: out = (z-mean)*rstd*gamma + beta + x ------------------
__global__ __launch_bounds__(256) void finalize_k(
    const float* __restrict__ z, const float* __restrict__ x,
    const float* __restrict__ mean, const float* __restrict__ rstd,
    const float* __restrict__ gamma, const float* __restrict__ beta,
    float* __restrict__ out)
{
  const int total = B_SZ * CIN * NN / 4;
  for (int i = blockIdx.x * blockDim.x + threadIdx.x; i < total;
       i += gridDim.x * blockDim.x){
    const int c = (i >> 10) & (CIN - 1);
    float4 zv = ((const float4*)z)[i];
    float4 xv = ((const float4*)x)[i];
    const float m = mean[c], r = rstd[c], ga = gamma[c], be = beta[c];
    float4 o;
    o.x = (zv.x - m) * r * ga + be + xv.x;
    o.y = (zv.y - m) * r * ga + be + xv.y;
    o.z = (zv.z - m) * r * ga + be + xv.z;
    o.w = (zv.w - m) * r * ga + be + xv.w;
    ((float4*)out)[i] = o;
  }
}

// ---------------- launcher --------------------------------------------------
extern "C" void kernel_launch(void* const* d_in, const int* in_sizes, int n_in,
                              void* d_out, int out_size, void* d_ws, size_t ws_size,
                              hipStream_t stream)
{
  const float* x     = (const float*)d_in[0];
  const float* Wt    = (const float*)d_in[1];
  const float* Wp    = (const float*)d_in[2];
  const float* Wg    = (const float*)d_in[3];
  const float* Wz    = (const float*)d_in[4];
  const float* gamma = (const float*)d_in[5];
  const float* beta  = (const float*)d_in[6];
  float* out = (float*)d_out;

  const size_t tpg_f  = (size_t)B_SZ * CP * NN;           // 2,097,152 each
  const size_t y_f    = (size_t)KSPLIT * B_SZ * CP * NN;  // 8,388,608
  const size_t z_f    = (size_t)B_SZ * CIN * NN;          // 4,194,304
  const size_t misc_f = 2 * (size_t)B_SZ * NN + 2 * CIN;
  const size_t rest_f = 3 * tpg_f + y_f + z_f + misc_f;
  const size_t full_need = ((size_t)B_SZ * NN * NN + rest_f) * sizeof(float);
  const bool full = (ws_size >= full_need);
  const size_t s_floats = full ? (size_t)B_SZ * NN * NN : (size_t)NN * NN;

  float* wsf = (float*)d_ws;
  size_t off = 0;
  float* S      = wsf + off; off += s_floats;
  float* tb     = wsf + off; off += tpg_f;
  float* pb     = wsf + off; off += tpg_f;
  float* gb     = wsf + off; off += tpg_f;
  float* yb     = wsf + off; off += y_f;
  float* zb     = wsf + off; off += z_f;
  float* rowmax = wsf + off; off += (size_t)B_SZ * NN;
  float* rowrls = wsf + off; off += (size_t)B_SZ * NN;
  float* meanb  = wsf + off; off += CIN;
  float* rstdb  = wsf + off; off += CIN;

  tpg_gemm<<<dim3(32, 3, B_SZ), 256, 0, stream>>>(Wt, Wp, Wg, x, tb, pb, gb);

  if (full){
    s_gemm   <<<dim3(32, 32, B_SZ), 256, 0, stream>>>(pb, tb, S, 0);
    row_stats<<<dim3(NN, 1, B_SZ),  256, 0, stream>>>(S, rowmax, rowrls, 0);
    y_gemm   <<<dim3(64, KSPLIT, B_SZ), 256, 0, stream>>>(gb, S, rowmax, rowrls, yb, 0);
  } else {
    for (int b = 0; b < B_SZ; ++b){
      s_gemm   <<<dim3(32, 32, 1), 256, 0, stream>>>(pb, tb, S, b);
      row_stats<<<dim3(NN, 1, 1),  256, 0, stream>>>(S, rowmax, rowrls, b);
      y_gemm   <<<dim3(64, KSPLIT, 1), 256, 0, stream>>>(gb, S, rowmax, rowrls, yb, b);
    }
  }

  z_gemm   <<<dim3(64, 2, B_SZ), 256, 0, stream>>>(Wz, yb, zb);
  bn_stats <<<dim3(CIN), 256, 0, stream>>>(zb, meanb, rstdb);
  finalize_k<<<dim3(2048), 256, 0, stream>>>(zb, x, meanb, rstdb, gamma, beta, out);
}

// Round 3
// 577.665 us; speedup vs baseline: 1.2346x; 1.2346x over previous
//
#include <hip/hip_runtime.h>
#include <hip/hip_bf16.h>
#include <hip/hip_fp16.h>

#define B_SZ 4
#define CIN  256
#define CP   128
#define NN   4096
#define KS   8

typedef _Float16 half_t;
typedef _Float16 f16x8 __attribute__((ext_vector_type(8)));
typedef float f32x4 __attribute__((ext_vector_type(4)));

// ---------------- wave reduction helpers (wave = 64 lanes) ----------------
__device__ __forceinline__ float wave_sum64(float v){
  #pragma unroll
  for (int o = 32; o > 0; o >>= 1) v += __shfl_xor(v, o, 64);
  return v;
}

// ---------------- K1: t/p/g = W{t,p,g} @ x_b  -------------------------------
// Outputs: sel 0 -> tT_hi/tT_lo ([B][NN][CP] fp16, transposed + split)
//          sel 1 -> pT_hi/pT_lo (same layout)
//          sel 2 -> gF ([B][CP][NN] fp16, natural layout)
__global__ __launch_bounds__(256) void tpg_gemm(
    const float* __restrict__ Wt, const float* __restrict__ Wp,
    const float* __restrict__ Wg, const float* __restrict__ x,
    half_t* __restrict__ tTh, half_t* __restrict__ tTl,
    half_t* __restrict__ pTh, half_t* __restrict__ pTl,
    half_t* __restrict__ gF)
{
  const int b   = blockIdx.z;
  const int sel = blockIdx.y;
  const int n0  = blockIdx.x * 128;
  const float* W = (sel == 0) ? Wt : ((sel == 1) ? Wp : Wg);
  const float* xb = x + (size_t)b * CIN * NN;

  __shared__ float a_s[32][132];  // [k][c], padded
  __shared__ float b_s[32][128];  // [k][n]
  __shared__ float ldsT[128][68]; // transpose bounce [n][c-half]

  const int tid = threadIdx.x;
  const int tx = tid & 15, ty = tid >> 4;

  float acc[2][2][4][4];
  #pragma unroll
  for (int qa = 0; qa < 2; ++qa)
    #pragma unroll
    for (int qb = 0; qb < 2; ++qb)
      #pragma unroll
      for (int i = 0; i < 4; ++i)
        #pragma unroll
        for (int j = 0; j < 4; ++j) acc[qa][qb][i][j] = 0.f;

  for (int k0 = 0; k0 < CIN; k0 += 32){
    #pragma unroll
    for (int i = 0; i < 4; ++i){
      int f4i = tid + i * 256;
      int c  = f4i >> 3;
      int k4 = f4i & 7;
      float4 w = *(const float4*)(W + (size_t)c * CIN + k0 + k4 * 4);
      a_s[k4*4+0][c] = w.x;
      a_s[k4*4+1][c] = w.y;
      a_s[k4*4+2][c] = w.z;
      a_s[k4*4+3][c] = w.w;
    }
    #pragma unroll
    for (int i = 0; i < 4; ++i){
      int f4i = tid + i * 256;
      int kk = f4i >> 5;
      int n4 = f4i & 31;
      *(float4*)&b_s[kk][n4*4] =
          *(const float4*)(xb + (size_t)(k0 + kk) * NN + n0 + n4 * 4);
    }
    __syncthreads();
    #pragma unroll
    for (int kk = 0; kk < 32; ++kk){
      float af[8], bf[8];
      *(float4*)&af[0] = *(const float4*)&a_s[kk][ty*4];
      *(float4*)&af[4] = *(const float4*)&a_s[kk][ty*4+64];
      *(float4*)&bf[0] = *(const float4*)&b_s[kk][tx*4];
      *(float4*)&bf[4] = *(const float4*)&b_s[kk][tx*4+64];
      #pragma unroll
      for (int qa = 0; qa < 2; ++qa)
        #pragma unroll
        for (int i = 0; i < 4; ++i)
          #pragma unroll
          for (int qb = 0; qb < 2; ++qb)
            #pragma unroll
            for (int j = 0; j < 4; ++j)
              acc[qa][qb][i][j] = fmaf(af[qa*4+i], bf[qb*4+j], acc[qa][qb][i][j]);
    }
    __syncthreads();
  }

  if (sel < 2){
    half_t* Ohi = ((sel == 0) ? tTh : pTh) + (size_t)b * NN * CP;
    half_t* Olo = ((sel == 0) ? tTl : pTl) + (size_t)b * NN * CP;
    for (int qa = 0; qa < 2; ++qa){
      #pragma unroll
      for (int qb = 0; qb < 2; ++qb)
        #pragma unroll
        for (int i = 0; i < 4; ++i)
          #pragma unroll
          for (int j = 0; j < 4; ++j)
            ldsT[qb*64 + tx*4 + j][ty*4 + i] = acc[qa][qb][i][j];
      __syncthreads();
      #pragma unroll
      for (int it = 0; it < 16; ++it){
        int idx = tid + it * 256;
        int nl = idx >> 5;
        int c0 = (idx & 31) * 2;
        float v0 = ldsT[nl][c0], v1 = ldsT[nl][c0+1];
        half_t h0 = (half_t)v0, h1 = (half_t)v1;
        half_t l0 = (half_t)(v0 - (float)h0), l1 = (half_t)(v1 - (float)h1);
        union { half_t h[2]; unsigned int u; } ph, pl;
        ph.h[0] = h0; ph.h[1] = h1;
        pl.h[0] = l0; pl.h[1] = l1;
        *(unsigned int*)(Ohi + (size_t)(n0 + nl) * CP + qa*64 + c0) = ph.u;
        *(unsigned int*)(Olo + (size_t)(n0 + nl) * CP + qa*64 + c0) = pl.u;
      }
      __syncthreads();
    }
  } else {
    half_t* G = gF + (size_t)b * CP * NN;
    #pragma unroll
    for (int qa = 0; qa < 2; ++qa)
      #pragma unroll
      for (int qb = 0; qb < 2; ++qb)
        #pragma unroll
        for (int i = 0; i < 4; ++i){
          int row = qa*64 + ty*4 + i;
          union { half_t h[4]; uint2 u2; } pg;
          #pragma unroll
          for (int j = 0; j < 4; ++j) pg.h[j] = (half_t)acc[qa][qb][i][j];
          *(uint2*)(G + (size_t)row * NN + n0 + qb*64 + tx*4) = pg.u2;
        }
  }
}

// ---------------- K2: S^T[n][m] = sum_c t[c][n]*p[c][m], fp16 3-slab MFMA ---
// A = tT (rows n, k=c contiguous), B = pT (rows m). One batch per launch.
__global__ __launch_bounds__(256) void s_gemm(
    const half_t* __restrict__ tTh, const half_t* __restrict__ tTl,
    const half_t* __restrict__ pTh, const half_t* __restrict__ pTl,
    float* __restrict__ ST, int b)
{
  const int m0 = blockIdx.x * 128;
  const int n0 = blockIdx.y * 128;
  const size_t tb = (size_t)b * NN * CP;
  __shared__ half_t As[128*64];
  __shared__ half_t Bs[128*64];
  const int tid = threadIdx.x;
  const int wid = tid >> 6, lane = tid & 63;
  const int wn = wid >> 1, wm = wid & 1;
  const int lr = lane & 15, lq = lane >> 4;

  f32x4 acc[4][4];
  #pragma unroll
  for (int i = 0; i < 4; ++i)
    #pragma unroll
    for (int j = 0; j < 4; ++j) acc[i][j] = (f32x4){0.f,0.f,0.f,0.f};

  // slabs: s0,1 = hi*hi; s2,3 = lo*hi; s4,5 = hi*lo  (each 64-wide k-chunk)
  #pragma unroll 1
  for (int s = 0; s < 6; ++s){
    const half_t* Ap = (s == 2 || s == 3) ? tTl : tTh;
    const half_t* Bp = (s >= 4) ? pTl : pTh;
    const int kc = (s & 1) * 64;
    #pragma unroll
    for (int p = 0; p < 4; ++p){
      int ug = tid + p * 256;
      int row = ug >> 3, u = ug & 7;
      uint4 va = *(const uint4*)(Ap + tb + (size_t)(n0 + row) * CP + kc + u * 8);
      uint4 vb = *(const uint4*)(Bp + tb + (size_t)(m0 + row) * CP + kc + u * 8);
      int widx = row * 64 + ((u * 8) ^ ((row & 7) * 8));
      *(uint4*)(As + widx) = va;
      *(uint4*)(Bs + widx) = vb;
    }
    __syncthreads();
    #pragma unroll
    for (int kk = 0; kk < 2; ++kk){
      f16x8 af[4], bf[4];
      #pragma unroll
      for (int f = 0; f < 4; ++f){
        int rowA = wn * 64 + f * 16 + lr;
        af[f] = *(const f16x8*)(As + rowA * 64 + ((kk*32 + lq*8) ^ ((rowA & 7) * 8)));
        int rowB = wm * 64 + f * 16 + lr;
        bf[f] = *(const f16x8*)(Bs + rowB * 64 + ((kk*32 + lq*8) ^ ((rowB & 7) * 8)));
      }
      #pragma unroll
      for (int fn = 0; fn < 4; ++fn)
        #pragma unroll
        for (int fm = 0; fm < 4; ++fm)
          acc[fn][fm] = __builtin_amdgcn_mfma_f32_16x16x32_f16(
              af[fn], bf[fm], acc[fn][fm], 0, 0, 0);
    }
    __syncthreads();
  }
  #pragma unroll
  for (int fn = 0; fn < 4; ++fn)
    #pragma unroll
    for (int r = 0; r < 4; ++r){
      int n = n0 + wn*64 + fn*16 + lq*4 + r;
      float* dst = ST + (size_t)n * NN + m0 + wm*64 + lr;
      #pragma unroll
      for (int fm = 0; fm < 4; ++fm) dst[fm*16] = acc[fn][fm][r];
    }
}

// ---------------- K3a: per-column (m) online max/sumexp partials ------------
// ST is [n][m]; stats are over n for fixed m. Partials over 256-row chunks.
__global__ __launch_bounds__(256) void col_stats(
    const float* __restrict__ ST, float* __restrict__ pmax,
    float* __restrict__ psum)
{
  const int tid = threadIdx.x;
  const int c = tid & 127, h = tid >> 7;
  const int m = blockIdx.x * 128 + c;
  const int nb = blockIdx.y * 256;
  float mx = -3.0e38f, sm = 0.f;
  #pragma unroll 4
  for (int r = 0; r < 128; ++r){
    float v = ST[(size_t)(nb + r*2 + h) * NN + m];
    if (v > mx){ sm = sm * __expf(mx - v) + 1.f; mx = v; }
    else sm += __expf(v - mx);
  }
  __shared__ float mx_s[256], sm_s[256];
  mx_s[tid] = mx; sm_s[tid] = sm;
  __syncthreads();
  if (tid < 128){
    float m1 = mx_s[tid + 128], s1 = sm_s[tid + 128];
    float nm = fmaxf(mx, m1);
    float S = sm * __expf(mx - nm) + s1 * __expf(m1 - nm);
    pmax[(size_t)blockIdx.y * NN + m] = nm;
    psum[(size_t)blockIdx.y * NN + m] = S;
  }
}

// ---------------- K3b: merge the 16 chunk partials --------------------------
__global__ __launch_bounds__(256) void merge_stats(
    const float* __restrict__ pmax, const float* __restrict__ psum,
    float* __restrict__ rowmax, float* __restrict__ rowrls)
{
  const int m = blockIdx.x * 256 + threadIdx.x;
  float mx = -3.0e38f, sm = 0.f;
  #pragma unroll
  for (int nc = 0; nc < 16; ++nc){
    float m1 = pmax[(size_t)nc * NN + m];
    float s1 = psum[(size_t)nc * NN + m];
    float nm = fmaxf(mx, m1);
    sm = sm * __expf(mx - nm) + s1 * __expf(m1 - nm);
    mx = nm;
  }
  rowmax[m] = mx;
  rowrls[m] = 1.f / sm;
}

// ---------------- K4: y_partial[c][n] += g[c][m] * E[m][n], fp16 MFMA -------
// A = gF (rows c, k=m contiguous), B = E staged from ST rows (exp in staging).
__global__ __launch_bounds__(256) void y_gemm(
    const half_t* __restrict__ gF, const float* __restrict__ ST,
    const float* __restrict__ rowmax, const float* __restrict__ rowrls,
    float* __restrict__ yp, int b)
{
  const int n0 = blockIdx.x * 64;
  const int ks = blockIdx.y;
  const int mbase = ks * (NN / KS);
  const half_t* G = gF + (size_t)b * CP * NN;
  __shared__ half_t As[128*64];
  __shared__ half_t Bs[64*64];
  const int tid = threadIdx.x;
  const int wid = tid >> 6, lane = tid & 63;
  const int wc = wid >> 1, wn2 = wid & 1;
  const int lr = lane & 15, lq = lane >> 4;

  f32x4 acc[4][2];
  #pragma unroll
  for (int i = 0; i < 4; ++i)
    #pragma unroll
    for (int j = 0; j < 2; ++j) acc[i][j] = (f32x4){0.f,0.f,0.f,0.f};

  #pragma unroll 1
  for (int st = 0; st < (NN/KS)/64; ++st){
    const int mc = mbase + st * 64;
    #pragma unroll
    for (int p = 0; p < 4; ++p){
      int ug = tid + p * 256;
      int row = ug >> 3, u = ug & 7;
      uint4 v = *(const uint4*)(G + (size_t)row * NN + mc + u * 8);
      *(uint4*)(As + row * 64 + ((u*8) ^ ((row & 7) * 8))) = v;
    }
    #pragma unroll
    for (int p = 0; p < 4; ++p){
      int f = tid + p * 256;
      int r = f >> 4, q = f & 15;
      int mm = mc + q * 4;
      float4 s4  = *(const float4*)(ST + (size_t)(n0 + r) * NN + mm);
      float4 mx4 = *(const float4*)(rowmax + mm);
      float4 rl4 = *(const float4*)(rowrls + mm);
      union { half_t h[4]; uint2 u2; } pk;
      pk.h[0] = (half_t)(__expf(s4.x - mx4.x) * rl4.x);
      pk.h[1] = (half_t)(__expf(s4.y - mx4.y) * rl4.y);
      pk.h[2] = (half_t)(__expf(s4.z - mx4.z) * rl4.z);
      pk.h[3] = (half_t)(__expf(s4.w - mx4.w) * rl4.w);
      *(uint2*)(Bs + r * 64 + ((q*4) ^ ((r & 7) * 8))) = pk.u2;
    }
    __syncthreads();
    #pragma unroll
    for (int kk = 0; kk < 2; ++kk){
      f16x8 af[4], bf[2];
      #pragma unroll
      for (int f = 0; f < 4; ++f){
        int rowA = wc*64 + f*16 + lr;
        af[f] = *(const f16x8*)(As + rowA*64 + ((kk*32 + lq*8) ^ ((rowA & 7)*8)));
      }
      #pragma unroll
      for (int f = 0; f < 2; ++f){
        int rowB = wn2*32 + f*16 + lr;
        bf[f] = *(const f16x8*)(Bs + rowB*64 + ((kk*32 + lq*8) ^ ((rowB & 7)*8)));
      }
      #pragma unroll
      for (int fc = 0; fc < 4; ++fc)
        #pragma unroll
        for (int fn = 0; fn < 2; ++fn)
          acc[fc][fn] = __builtin_amdgcn_mfma_f32_16x16x32_f16(
              af[fc], bf[fn], acc[fc][fn], 0, 0, 0);
    }
    __syncthreads();
  }
  #pragma unroll
  for (int fc = 0; fc < 4; ++fc)
    #pragma unroll
    for (int r = 0; r < 4; ++r){
      int c = wc*64 + fc*16 + lq*4 + r;
      #pragma unroll
      for (int fn = 0; fn < 2; ++fn){
        int n = n0 + wn2*32 + fn*16 + lr;
        yp[((size_t)ks * CP + c) * NN + n] = acc[fc][fn][r];
      }
    }
}

// ---------------- K4b: fold KS partials into y[b] ---------------------------
__global__ __launch_bounds__(256) void fold_y(
    const float4* __restrict__ yp, float4* __restrict__ dst)
{
  const int i = blockIdx.x * 256 + threadIdx.x;  // 512*256 = CP*NN/4
  float4 a = yp[i];
  #pragma unroll
  for (int s = 1; s < KS; ++s){
    float4 v = yp[(size_t)s * (CP*NN/4) + i];
    a.x += v.x; a.y += v.y; a.z += v.z; a.w += v.w;
  }
  dst[i] = a;
}

// ---------------- K5: z = Wz @ y (fp32) -------------------------------------
__global__ __launch_bounds__(256) void z_gemm(
    const float* __restrict__ Wz, const float* __restrict__ y,
    float* __restrict__ z)
{
  const int b  = blockIdx.z;
  const int o0 = blockIdx.y * 128;
  const int n0 = blockIdx.x * 64;
  const float* yb = y + (size_t)b * CP * NN;
  float* zb = z + (size_t)b * CIN * NN;

  __shared__ float a_s[32][132];
  __shared__ float b_s[32][64];

  const int tid = threadIdx.x;
  const int tx = tid & 15, ty = tid >> 4;

  float acc[2][4][4];
  #pragma unroll
  for (int qa = 0; qa < 2; ++qa)
    #pragma unroll
    for (int i = 0; i < 4; ++i)
      #pragma unroll
      for (int j = 0; j < 4; ++j) acc[qa][i][j] = 0.f;

  for (int k0 = 0; k0 < CP; k0 += 32){
    #pragma unroll
    for (int i = 0; i < 4; ++i){
      int f4i = tid + i * 256;
      int c  = f4i >> 3;
      int k4 = f4i & 7;
      float4 w = *(const float4*)(Wz + (size_t)(o0 + c) * CP + k0 + k4 * 4);
      a_s[k4*4+0][c] = w.x;
      a_s[k4*4+1][c] = w.y;
      a_s[k4*4+2][c] = w.z;
      a_s[k4*4+3][c] = w.w;
    }
    #pragma unroll
    for (int i = 0; i < 2; ++i){
      int f4i = tid + i * 256;
      int kk = f4i >> 4;
      int n4 = f4i & 15;
      *(float4*)&b_s[kk][n4*4] =
          *(const float4*)(yb + (size_t)(k0 + kk) * NN + n0 + n4 * 4);
    }
    __syncthreads();
    #pragma unroll
    for (int kk = 0; kk < 32; ++kk){
      float af[8], bf[4];
      *(float4*)&af[0] = *(const float4*)&a_s[kk][ty*4];
      *(float4*)&af[4] = *(const float4*)&a_s[kk][ty*4+64];
      *(float4*)&bf[0] = *(const float4*)&b_s[kk][tx*4];
      #pragma unroll
      for (int qa = 0; qa < 2; ++qa)
        #pragma unroll
        for (int i = 0; i < 4; ++i)
          #pragma unroll
          for (int j = 0; j < 4; ++j)
            acc[qa][i][j] = fmaf(af[qa*4+i], bf[j], acc[qa][i][j]);
    }
    __syncthreads();
  }
  #pragma unroll
  for (int qa = 0; qa < 2; ++qa)
    #pragma unroll
    for (int i = 0; i < 4; ++i){
      const int row = o0 + qa*64 + ty*4 + i;
      float4 v = make_float4(acc[qa][i][0], acc[qa][i][1],
                             acc[qa][i][2], acc[qa][i][3]);
      *(float4*)(zb + (size_t)row * NN + n0 + tx*4) = v;
    }
}

// ---------------- K6: BatchNorm batch stats ---------------------------------
__global__ __launch_bounds__(256) void bn_stats(
    const float* __restrict__ z, float* __restrict__ mean,
    float* __restrict__ rstd)
{
  const int c = blockIdx.x;
  const int tid = threadIdx.x;
  float s = 0.f, s2 = 0.f;
  for (int b = 0; b < B_SZ; ++b){
    const float4* row = (const float4*)(z + ((size_t)b * CIN + c) * NN);
    #pragma unroll
    for (int i = 0; i < 4; ++i){
      float4 v = row[tid + i*256];
      s  += v.x + v.y + v.z + v.w;
      s2 += v.x*v.x + v.y*v.y + v.z*v.z + v.w*v.w;
    }
  }
  s  = wave_sum64(s);
  s2 = wave_sum64(s2);
  __shared__ float rs[4];
  __shared__ float rq[4];
  const int wid = tid >> 6, lane = tid & 63;
  if (lane == 0){ rs[wid] = s; rq[wid] = s2; }
  __syncthreads();
  if (tid == 0){
    const float S1 = rs[0]+rs[1]+rs[2]+rs[3];
    const float S2 = rq[0]+rq[1]+rq[2]+rq[3];
    const float inv = 1.f / (float)(B_SZ * NN);
    const float m = S1 * inv;
    const float var = S2 * inv - m * m;
    mean[c] = m;
    rstd[c] = 1.f / sqrtf(var + 1e-5f);
  }
}

// ---------------- K7: out = (z-mean)*rstd*gamma + beta + x ------------------
__global__ __launch_bounds__(256) void finalize_k(
    const float* __restrict__ z, const float* __restrict__ x,
    const float* __restrict__ mean, const float* __restrict__ rstd,
    const float* __restrict__ gamma, const float* __restrict__ beta,
    float* __restrict__ out)
{
  const int total = B_SZ * CIN * NN / 4;
  for (int i = blockIdx.x * blockDim.x + threadIdx.x; i < total;
       i += gridDim.x * blockDim.x){
    const int c = (i >> 10) & (CIN - 1);
    float4 zv = ((const float4*)z)[i];
    float4 xv = ((const float4*)x)[i];
    const float m = mean[c], r = rstd[c], ga = gamma[c], be = beta[c];
    float4 o;
    o.x = (zv.x - m) * r * ga + be + xv.x;
    o.y = (zv.y - m) * r * ga + be + xv.y;
    o.z = (zv.z - m) * r * ga + be + xv.z;
    o.w = (zv.w - m) * r * ga + be + xv.w;
    ((float4*)out)[i] = o;
  }
}

// ---------------- launcher --------------------------------------------------
extern "C" void kernel_launch(void* const* d_in, const int* in_sizes, int n_in,
                              void* d_out, int out_size, void* d_ws, size_t ws_size,
                              hipStream_t stream)
{
  const float* x     = (const float*)d_in[0];
  const float* Wt    = (const float*)d_in[1];
  const float* Wp    = (const float*)d_in[2];
  const float* Wg    = (const float*)d_in[3];
  const float* Wz    = (const float*)d_in[4];
  const float* gamma = (const float*)d_in[5];
  const float* beta  = (const float*)d_in[6];
  float* out = (float*)d_out;

  float* wsf = (float*)d_ws;
  size_t off = 0;
  float*  ST   = wsf + off; off += (size_t)NN * NN;            // 16.78M f (64MB)
  half_t* tTh  = (half_t*)(wsf + off); off += (size_t)B_SZ*NN*CP/2;
  half_t* tTl  = (half_t*)(wsf + off); off += (size_t)B_SZ*NN*CP/2;
  half_t* pTh  = (half_t*)(wsf + off); off += (size_t)B_SZ*NN*CP/2;
  half_t* pTl  = (half_t*)(wsf + off); off += (size_t)B_SZ*NN*CP/2;
  half_t* gF   = (half_t*)(wsf + off); off += (size_t)B_SZ*CP*NN/2;
  float*  yp   = wsf + off; off += (size_t)KS * CP * NN;       // per-batch reuse
  float*  y    = wsf + off; off += (size_t)B_SZ * CP * NN;
  float*  pmax = wsf + off; off += (size_t)16 * NN;
  float*  psum = wsf + off; off += (size_t)16 * NN;
  float*  rmx  = wsf + off; off += NN;
  float*  rls  = wsf + off; off += NN;
  float*  meanb= wsf + off; off += CIN;
  float*  rstdb= wsf + off; off += CIN;
  float*  z    = ST;  // alias: ST is dead once the batch loop finishes

  tpg_gemm<<<dim3(32, 3, B_SZ), 256, 0, stream>>>(Wt, Wp, Wg, x,
                                                  tTh, tTl, pTh, pTl, gF);

  for (int b = 0; b < B_SZ; ++b){
    s_gemm     <<<dim3(32, 32), 256, 0, stream>>>(tTh, tTl, pTh, pTl, ST, b);
    col_stats  <<<dim3(32, 16), 256, 0, stream>>>(ST, pmax, psum);
    merge_stats<<<dim3(16),     256, 0, stream>>>(pmax, psum, rmx, rls);
    y_gemm     <<<dim3(64, KS), 256, 0, stream>>>(gF, ST, rmx, rls, yp, b);
    fold_y     <<<dim3(512),    256, 0, stream>>>((const float4*)yp,
                                                  (float4*)(y + (size_t)b*CP*NN));
  }

  z_gemm   <<<dim3(64, 2, B_SZ), 256, 0, stream>>>(Wz, y, z);
  bn_stats <<<dim3(CIN), 256, 0, stream>>>(z, meanb, rstdb);
  finalize_k<<<dim3(2048), 256, 0, stream>>>(z, x, meanb, rstdb, gamma, beta, out);
}

// Round 4
// 333.659 us; speedup vs baseline: 2.1374x; 1.7313x over previous
//
#include <hip/hip_runtime.h>
#include <hip/hip_fp16.h>

#define B_SZ 4
#define CIN  256
#define CP   128
#define NN   4096
#define NT   32          // 128-row n-tiles per batch (softmax partials)
#define KSL  16          // k-slices in y_gemm

typedef _Float16 half_t;
typedef _Float16 f16x8 __attribute__((ext_vector_type(8)));
typedef float f32x4 __attribute__((ext_vector_type(4)));

#define GPTR(p) ((const __attribute__((address_space(1))) void*)(p))
#define LPTR(p) ((__attribute__((address_space(3))) void*)(p))

__device__ __forceinline__ float wave_sum64(float v){
  #pragma unroll
  for (int o = 32; o > 0; o >>= 1) v += __shfl_xor(v, o, 64);
  return v;
}

// ---------------- K1: t/p/g = W{t,p,g} @ x_b --------------------------------
// sel 0 -> tT hi/lo ([B][NN][CP] fp16), sel 1 -> pT hi/lo, sel 2 -> gF [B][CP][NN]
__global__ __launch_bounds__(256) void tpg_gemm(
    const float* __restrict__ Wt, const float* __restrict__ Wp,
    const float* __restrict__ Wg, const float* __restrict__ x,
    half_t* __restrict__ tTh, half_t* __restrict__ tTl,
    half_t* __restrict__ pTh, half_t* __restrict__ pTl,
    half_t* __restrict__ gF)
{
  const int b   = blockIdx.z;
  const int sel = blockIdx.y;
  const int n0  = blockIdx.x * 64;
  const float* W = (sel == 0) ? Wt : ((sel == 1) ? Wp : Wg);
  const float* xb = x + (size_t)b * CIN * NN;

  __shared__ float pool[6272];               // 25 KB
  float (*a_s)[132] = (float (*)[132])pool;  // [32 k][128 c] padded
  float (*b_s)[64]  = (float (*)[64])(pool + 32*132);
  float (*ldsT)[68] = (float (*)[68])pool;   // epilogue alias [64 n][64 c]

  const int tid = threadIdx.x;
  const int tx = tid & 15, ty = tid >> 4;

  float acc[2][4][4];
  #pragma unroll
  for (int qa = 0; qa < 2; ++qa)
    #pragma unroll
    for (int i = 0; i < 4; ++i)
      #pragma unroll
      for (int j = 0; j < 4; ++j) acc[qa][i][j] = 0.f;

  for (int k0 = 0; k0 < CIN; k0 += 32){
    #pragma unroll
    for (int i = 0; i < 4; ++i){
      int f4i = tid + i * 256;
      int c  = f4i >> 3;
      int k4 = f4i & 7;
      float4 w = *(const float4*)(W + (size_t)c * CIN + k0 + k4 * 4);
      a_s[k4*4+0][c] = w.x;
      a_s[k4*4+1][c] = w.y;
      a_s[k4*4+2][c] = w.z;
      a_s[k4*4+3][c] = w.w;
    }
    #pragma unroll
    for (int i = 0; i < 2; ++i){
      int f4i = tid + i * 256;
      int kk = f4i >> 4;
      int n4 = f4i & 15;
      *(float4*)&b_s[kk][n4*4] =
          *(const float4*)(xb + (size_t)(k0 + kk) * NN + n0 + n4 * 4);
    }
    __syncthreads();
    #pragma unroll
    for (int kk = 0; kk < 32; ++kk){
      float af[8], bf[4];
      *(float4*)&af[0] = *(const float4*)&a_s[kk][ty*4];
      *(float4*)&af[4] = *(const float4*)&a_s[kk][ty*4+64];
      *(float4*)&bf[0] = *(const float4*)&b_s[kk][tx*4];
      #pragma unroll
      for (int qa = 0; qa < 2; ++qa)
        #pragma unroll
        for (int i = 0; i < 4; ++i)
          #pragma unroll
          for (int j = 0; j < 4; ++j)
            acc[qa][i][j] = fmaf(af[qa*4+i], bf[j], acc[qa][i][j]);
    }
    __syncthreads();
  }

  if (sel < 2){
    half_t* Ohi = ((sel == 0) ? tTh : pTh) + (size_t)b * NN * CP;
    half_t* Olo = ((sel == 0) ? tTl : pTl) + (size_t)b * NN * CP;
    for (int qa = 0; qa < 2; ++qa){
      #pragma unroll
      for (int j = 0; j < 4; ++j){
        float4 v = make_float4(acc[qa][0][j], acc[qa][1][j],
                               acc[qa][2][j], acc[qa][3][j]);
        *(float4*)&ldsT[tx*4+j][ty*4] = v;
      }
      __syncthreads();
      #pragma unroll
      for (int it = 0; it < 8; ++it){
        int idx = tid + it * 256;          // 2048 pairs
        int nl = idx >> 5;
        int c0 = (idx & 31) * 2;
        float2 v = *(const float2*)&ldsT[nl][c0];
        half_t h0 = (half_t)v.x, h1 = (half_t)v.y;
        half_t l0 = (half_t)(v.x - (float)h0), l1 = (half_t)(v.y - (float)h1);
        union { half_t h[2]; unsigned int u; } ph, pl;
        ph.h[0] = h0; ph.h[1] = h1;
        pl.h[0] = l0; pl.h[1] = l1;
        *(unsigned int*)(Ohi + (size_t)(n0 + nl) * CP + qa*64 + c0) = ph.u;
        *(unsigned int*)(Olo + (size_t)(n0 + nl) * CP + qa*64 + c0) = pl.u;
      }
      __syncthreads();
    }
  } else {
    half_t* G = gF + (size_t)b * CP * NN;
    #pragma unroll
    for (int qa = 0; qa < 2; ++qa)
      #pragma unroll
      for (int i = 0; i < 4; ++i){
        int row = qa*64 + ty*4 + i;
        union { half_t h[4]; uint2 u2; } pg;
        #pragma unroll
        for (int j = 0; j < 4; ++j) pg.h[j] = (half_t)acc[qa][i][j];
        *(uint2*)(G + (size_t)row * NN + n0 + tx*4) = pg.u2;
      }
  }
}

// ---------------- K2: S^T tile + fused col-stats + E(fp16) store ------------
// ST[n][m] logits via 3-slab fp16 MFMA; epilogue computes per-column(m) tile
// max/sumexp partials and stores E = exp(S - tilemax) as fp16.
__global__ __launch_bounds__(256) void s_gemm(
    const half_t* __restrict__ tTh, const half_t* __restrict__ tTl,
    const half_t* __restrict__ pTh, const half_t* __restrict__ pTl,
    half_t* __restrict__ ST, float* __restrict__ pmax,
    float* __restrict__ psum, int b)
{
  const int m0 = blockIdx.x * 128;
  const int n0 = blockIdx.y * 128;
  const size_t tb = (size_t)b * NN * CP;
  __shared__ half_t lds[4 * 128 * 64];       // Ah | Al | Bh | Bl, 64 KB
  const int tid = threadIdx.x;
  const int wid = tid >> 6, lane = tid & 63;
  const int wn = wid >> 1, wm = wid & 1;
  const int lr = lane & 15, lq = lane >> 4;

  f32x4 acc[4][4];
  #pragma unroll
  for (int i = 0; i < 4; ++i)
    #pragma unroll
    for (int j = 0; j < 4; ++j) acc[i][j] = (f32x4){0.f,0.f,0.f,0.f};

  const half_t* baseA_h = tTh + tb + (size_t)n0 * CP;
  const half_t* baseA_l = tTl + tb + (size_t)n0 * CP;
  const half_t* baseB_h = pTh + tb + (size_t)m0 * CP;
  const half_t* baseB_l = pTl + tb + (size_t)m0 * CP;

  #pragma unroll 1
  for (int kc = 0; kc < CP; kc += 64){
    // stage 4 tiles of [128 rows][64 k] via global_load_lds, swizzled source
    #pragma unroll
    for (int it = 0; it < 4; ++it){
      int seg = wid * 4 + it;                 // wave-uniform
      int row = seg * 8 + (lane >> 3);
      int us  = (lane & 7) ^ (row & 7);
      size_t go = (size_t)row * CP + kc + us * 8;
      gloadA: ;
      __builtin_amdgcn_global_load_lds(GPTR(baseA_h + go), LPTR(lds + seg*512), 16, 0, 0);
      __builtin_amdgcn_global_load_lds(GPTR(baseA_l + go), LPTR(lds + 8192 + seg*512), 16, 0, 0);
      __builtin_amdgcn_global_load_lds(GPTR(baseB_h + go), LPTR(lds + 16384 + seg*512), 16, 0, 0);
      __builtin_amdgcn_global_load_lds(GPTR(baseB_l + go), LPTR(lds + 24576 + seg*512), 16, 0, 0);
    }
    asm volatile("s_waitcnt vmcnt(0)" ::: "memory");
    __syncthreads();

    #pragma unroll
    for (int kk = 0; kk < 2; ++kk){
      f16x8 ah[4], al[4], bh[4], bl[4];
      #pragma unroll
      for (int f = 0; f < 4; ++f){
        int rA = wn*64 + f*16 + lr;
        int cA = (kk*32 + lq*8) ^ ((rA & 7) * 8);
        ah[f] = *(const f16x8*)(lds + rA*64 + cA);
        al[f] = *(const f16x8*)(lds + 8192 + rA*64 + cA);
        int rB = wm*64 + f*16 + lr;
        int cB = (kk*32 + lq*8) ^ ((rB & 7) * 8);
        bh[f] = *(const f16x8*)(lds + 16384 + rB*64 + cB);
        bl[f] = *(const f16x8*)(lds + 24576 + rB*64 + cB);
      }
      #pragma unroll
      for (int fn = 0; fn < 4; ++fn)
        #pragma unroll
        for (int fm = 0; fm < 4; ++fm){
          acc[fn][fm] = __builtin_amdgcn_mfma_f32_16x16x32_f16(ah[fn], bh[fm], acc[fn][fm], 0,0,0);
          acc[fn][fm] = __builtin_amdgcn_mfma_f32_16x16x32_f16(al[fn], bh[fm], acc[fn][fm], 0,0,0);
          acc[fn][fm] = __builtin_amdgcn_mfma_f32_16x16x32_f16(ah[fn], bl[fm], acc[fn][fm], 0,0,0);
        }
    }
    __syncthreads();
  }

  // ---- fused column-stats epilogue (stats over n per column m) ----
  float* red  = (float*)lds;        // [4 wid][4 fm][16 lr]
  float* red2 = (float*)lds + 256;

  float cmax[4];
  #pragma unroll
  for (int fm = 0; fm < 4; ++fm){
    float t = -3.0e38f;
    #pragma unroll
    for (int fn = 0; fn < 4; ++fn)
      #pragma unroll
      for (int r = 0; r < 4; ++r) t = fmaxf(t, acc[fn][fm][r]);
    t = fmaxf(t, __shfl_xor(t, 16, 64));
    t = fmaxf(t, __shfl_xor(t, 32, 64));
    cmax[fm] = t;
  }
  if (lq == 0){
    #pragma unroll
    for (int fm = 0; fm < 4; ++fm) red[(wid*4+fm)*16 + lr] = cmax[fm];
  }
  __syncthreads();
  #pragma unroll
  for (int fm = 0; fm < 4; ++fm)
    cmax[fm] = fmaxf(red[((wm)*4+fm)*16 + lr], red[((2+wm)*4+fm)*16 + lr]);

  float csum[4] = {0.f, 0.f, 0.f, 0.f};
  #pragma unroll
  for (int fn = 0; fn < 4; ++fn)
    #pragma unroll
    for (int r = 0; r < 4; ++r){
      int n = n0 + wn*64 + fn*16 + lq*4 + r;
      half_t* dst = ST + (size_t)n * NN + m0 + wm*64;
      #pragma unroll
      for (int fm = 0; fm < 4; ++fm){
        float e = __expf(acc[fn][fm][r] - cmax[fm]);
        csum[fm] += e;
        dst[fm*16 + lr] = (half_t)e;
      }
    }
  #pragma unroll
  for (int fm = 0; fm < 4; ++fm){
    csum[fm] += __shfl_xor(csum[fm], 16, 64);
    csum[fm] += __shfl_xor(csum[fm], 32, 64);
  }
  __syncthreads();
  if (lq == 0){
    #pragma unroll
    for (int fm = 0; fm < 4; ++fm) red2[(wid*4+fm)*16 + lr] = csum[fm];
  }
  __syncthreads();
  if (wn == 0 && lq == 0){
    #pragma unroll
    for (int fm = 0; fm < 4; ++fm){
      int m = m0 + wm*64 + fm*16 + lr;
      pmax[(size_t)blockIdx.y * NN + m] = cmax[fm];
      psum[(size_t)blockIdx.y * NN + m] = red2[((wm)*4+fm)*16 + lr]
                                        + red2[((2+wm)*4+fm)*16 + lr];
    }
  }
}

// ---------------- K3: merge tile partials -> corr[nt][m] --------------------
__global__ __launch_bounds__(256) void merge_corr(
    const float* __restrict__ pmax, const float* __restrict__ psum,
    float* __restrict__ corr)
{
  const int m = blockIdx.x * 256 + threadIdx.x;
  float pm[NT];
  float mx = -3.0e38f;
  #pragma unroll
  for (int nt = 0; nt < NT; ++nt){
    pm[nt] = pmax[(size_t)nt * NN + m];
    mx = fmaxf(mx, pm[nt]);
  }
  float den = 0.f;
  #pragma unroll
  for (int nt = 0; nt < NT; ++nt){
    pm[nt] = __expf(pm[nt] - mx);
    den += psum[(size_t)nt * NN + m] * pm[nt];
  }
  const float r = 1.f / den;
  #pragma unroll
  for (int nt = 0; nt < NT; ++nt)
    corr[(size_t)nt * NN + m] = pm[nt] * r;
}

// ---------------- K4: yp[ks][c][n] = sum_m g[c][m] * (E[n][m]*corr) ---------
__global__ __launch_bounds__(256) void y_gemm(
    const half_t* __restrict__ gF, const half_t* __restrict__ ST,
    const float* __restrict__ corr, float* __restrict__ yp, int b)
{
  const int n0 = blockIdx.x * 128;
  const int nt = blockIdx.x;              // matches s_gemm n-tile (128)
  const int ks = blockIdx.y;              // 16 slices of 256 m
  const half_t* G = gF + (size_t)b * CP * NN;
  __shared__ half_t As[128*64];           // g[c][m-chunk]
  __shared__ half_t Bs[128*64];           // E'[n][m-chunk]
  const int tid = threadIdx.x;
  const int wid = tid >> 6, lane = tid & 63;
  const int wc = wid >> 1, wn = wid & 1;
  const int lr = lane & 15, lq = lane >> 4;

  f32x4 acc[4][4];
  #pragma unroll
  for (int i = 0; i < 4; ++i)
    #pragma unroll
    for (int j = 0; j < 4; ++j) acc[i][j] = (f32x4){0.f,0.f,0.f,0.f};

  #pragma unroll 1
  for (int st = 0; st < 4; ++st){
    const int mc = ks * 256 + st * 64;
    #pragma unroll
    for (int it = 0; it < 4; ++it){
      int seg = wid * 4 + it;
      int row = seg * 8 + (lane >> 3);
      int us  = (lane & 7) ^ (row & 7);
      __builtin_amdgcn_global_load_lds(GPTR(G + (size_t)row * NN + mc + us*8),
                                       LPTR(As + seg*512), 16, 0, 0);
    }
    #pragma unroll
    for (int i = 0; i < 8; ++i){
      int idx = tid + i * 256;             // 2048
      int r = idx >> 4;                    // n row 0..127
      int q = idx & 15;                    // m quad
      int mm = mc + q * 4;
      union { half_t h[4]; uint2 u2; } ev, eo;
      ev.u2 = *(const uint2*)(ST + (size_t)(n0 + r) * NN + mm);
      float4 cr = *(const float4*)(corr + (size_t)nt * NN + mm);
      eo.h[0] = (half_t)((float)ev.h[0] * cr.x);
      eo.h[1] = (half_t)((float)ev.h[1] * cr.y);
      eo.h[2] = (half_t)((float)ev.h[2] * cr.z);
      eo.h[3] = (half_t)((float)ev.h[3] * cr.w);
      int c4 = (q * 4) ^ ((r & 7) * 8);
      *(uint2*)(Bs + r * 64 + c4) = eo.u2;
    }
    asm volatile("s_waitcnt vmcnt(0)" ::: "memory");
    __syncthreads();

    #pragma unroll
    for (int kk = 0; kk < 2; ++kk){
      f16x8 af[4], bf[4];
      #pragma unroll
      for (int f = 0; f < 4; ++f){
        int rA = wc*64 + f*16 + lr;
        af[f] = *(const f16x8*)(As + rA*64 + ((kk*32 + lq*8) ^ ((rA & 7)*8)));
        int rB = wn*64 + f*16 + lr;
        bf[f] = *(const f16x8*)(Bs + rB*64 + ((kk*32 + lq*8) ^ ((rB & 7)*8)));
      }
      #pragma unroll
      for (int fc = 0; fc < 4; ++fc)
        #pragma unroll
        for (int fn = 0; fn < 4; ++fn)
          acc[fc][fn] = __builtin_amdgcn_mfma_f32_16x16x32_f16(af[fc], bf[fn], acc[fc][fn], 0,0,0);
    }
    __syncthreads();
  }
  #pragma unroll
  for (int fc = 0; fc < 4; ++fc)
    #pragma unroll
    for (int r = 0; r < 4; ++r){
      int c = wc*64 + fc*16 + lq*4 + r;
      float* dst = yp + ((size_t)ks * CP + c) * NN + n0 + wn*64;
      #pragma unroll
      for (int fn = 0; fn < 4; ++fn) dst[fn*16 + lr] = acc[fc][fn][r];
    }
}

// ---------------- K4b: fold KSL partials into y[b] --------------------------
__global__ __launch_bounds__(256) void fold_y(
    const float4* __restrict__ yp, float4* __restrict__ dst)
{
  const int i = blockIdx.x * 256 + threadIdx.x;   // 512*256 = CP*NN/4
  float4 a = yp[i];
  #pragma unroll
  for (int s = 1; s < KSL; ++s){
    float4 v = yp[(size_t)s * (CP*NN/4) + i];
    a.x += v.x; a.y += v.y; a.z += v.z; a.w += v.w;
  }
  dst[i] = a;
}

// ---------------- K5: z = Wz @ y (fp32) -------------------------------------
__global__ __launch_bounds__(256) void z_gemm(
    const float* __restrict__ Wz, const float* __restrict__ y,
    float* __restrict__ z)
{
  const int b  = blockIdx.z;
  const int o0 = blockIdx.y * 128;
  const int n0 = blockIdx.x * 64;
  const float* yb = y + (size_t)b * CP * NN;
  float* zb = z + (size_t)b * CIN * NN;

  __shared__ float a_s[32][132];
  __shared__ float b_s[32][64];

  const int tid = threadIdx.x;
  const int tx = tid & 15, ty = tid >> 4;

  float acc[2][4][4];
  #pragma unroll
  for (int qa = 0; qa < 2; ++qa)
    #pragma unroll
    for (int i = 0; i < 4; ++i)
      #pragma unroll
      for (int j = 0; j < 4; ++j) acc[qa][i][j] = 0.f;

  for (int k0 = 0; k0 < CP; k0 += 32){
    #pragma unroll
    for (int i = 0; i < 4; ++i){
      int f4i = tid + i * 256;
      int c  = f4i >> 3;
      int k4 = f4i & 7;
      float4 w = *(const float4*)(Wz + (size_t)(o0 + c) * CP + k0 + k4 * 4);
      a_s[k4*4+0][c] = w.x;
      a_s[k4*4+1][c] = w.y;
      a_s[k4*4+2][c] = w.z;
      a_s[k4*4+3][c] = w.w;
    }
    #pragma unroll
    for (int i = 0; i < 2; ++i){
      int f4i = tid + i * 256;
      int kk = f4i >> 4;
      int n4 = f4i & 15;
      *(float4*)&b_s[kk][n4*4] =
          *(const float4*)(yb + (size_t)(k0 + kk) * NN + n0 + n4 * 4);
    }
    __syncthreads();
    #pragma unroll
    for (int kk = 0; kk < 32; ++kk){
      float af[8], bf[4];
      *(float4*)&af[0] = *(const float4*)&a_s[kk][ty*4];
      *(float4*)&af[4] = *(const float4*)&a_s[kk][ty*4+64];
      *(float4*)&bf[0] = *(const float4*)&b_s[kk][tx*4];
      #pragma unroll
      for (int qa = 0; qa < 2; ++qa)
        #pragma unroll
        for (int i = 0; i < 4; ++i)
          #pragma unroll
          for (int j = 0; j < 4; ++j)
            acc[qa][i][j] = fmaf(af[qa*4+i], bf[j], acc[qa][i][j]);
    }
    __syncthreads();
  }
  #pragma unroll
  for (int qa = 0; qa < 2; ++qa)
    #pragma unroll
    for (int i = 0; i < 4; ++i){
      const int row = o0 + qa*64 + ty*4 + i;
      float4 v = make_float4(acc[qa][i][0], acc[qa][i][1],
                             acc[qa][i][2], acc[qa][i][3]);
      *(float4*)(zb + (size_t)row * NN + n0 + tx*4) = v;
    }
}

// ---------------- K6: BatchNorm batch stats ---------------------------------
__global__ __launch_bounds__(256) void bn_stats(
    const float* __restrict__ z, float* __restrict__ mean,
    float* __restrict__ rstd)
{
  const int c = blockIdx.x;
  const int tid = threadIdx.x;
  float s = 0.f, s2 = 0.f;
  for (int b = 0; b < B_SZ; ++b){
    const float4* row = (const float4*)(z + ((size_t)b * CIN + c) * NN);
    #pragma unroll
    for (int i = 0; i < 4; ++i){
      float4 v = row[tid + i*256];
      s  += v.x + v.y + v.z + v.w;
      s2 += v.x*v.x + v.y*v.y + v.z*v.z + v.w*v.w;
    }
  }
  s  = wave_sum64(s);
  s2 = wave_sum64(s2);
  __shared__ float rs[4];
  __shared__ float rq[4];
  const int wid = tid >> 6, lane = tid & 63;
  if (lane == 0){ rs[wid] = s; rq[wid] = s2; }
  __syncthreads();
  if (tid == 0){
    const float S1 = rs[0]+rs[1]+rs[2]+rs[3];
    const float S2 = rq[0]+rq[1]+rq[2]+rq[3];
    const float inv = 1.f / (float)(B_SZ * NN);
    const float m = S1 * inv;
    const float var = S2 * inv - m * m;
    mean[c] = m;
    rstd[c] = 1.f / sqrtf(var + 1e-5f);
  }
}

// ---------------- K7: out = (z-mean)*rstd*gamma + beta + x ------------------
__global__ __launch_bounds__(256) void finalize_k(
    const float* __restrict__ z, const float* __restrict__ x,
    const float* __restrict__ mean, const float* __restrict__ rstd,
    const float* __restrict__ gamma, const float* __restrict__ beta,
    float* __restrict__ out)
{
  const int total = B_SZ * CIN * NN / 4;
  for (int i = blockIdx.x * blockDim.x + threadIdx.x; i < total;
       i += gridDim.x * blockDim.x){
    const int c = (i >> 10) & (CIN - 1);
    float4 zv = ((const float4*)z)[i];
    float4 xv = ((const float4*)x)[i];
    const float m = mean[c], r = rstd[c], ga = gamma[c], be = beta[c];
    float4 o;
    o.x = (zv.x - m) * r * ga + be + xv.x;
    o.y = (zv.y - m) * r * ga + be + xv.y;
    o.z = (zv.z - m) * r * ga + be + xv.z;
    o.w = (zv.w - m) * r * ga + be + xv.w;
    ((float4*)out)[i] = o;
  }
}

// ---------------- launcher --------------------------------------------------
extern "C" void kernel_launch(void* const* d_in, const int* in_sizes, int n_in,
                              void* d_out, int out_size, void* d_ws, size_t ws_size,
                              hipStream_t stream)
{
  const float* x     = (const float*)d_in[0];
  const float* Wt    = (const float*)d_in[1];
  const float* Wp    = (const float*)d_in[2];
  const float* Wg    = (const float*)d_in[3];
  const float* Wz    = (const float*)d_in[4];
  const float* gamma = (const float*)d_in[5];
  const float* beta  = (const float*)d_in[6];
  float* out = (float*)d_out;

  float* wsf = (float*)d_ws;
  size_t off = 0;
  half_t* ST  = (half_t*)(wsf + off); off += (size_t)NN * NN / 2;      // 33.5MB
  half_t* tTh = (half_t*)(wsf + off); off += (size_t)B_SZ*NN*CP/2;
  half_t* tTl = (half_t*)(wsf + off); off += (size_t)B_SZ*NN*CP/2;
  half_t* pTh = (half_t*)(wsf + off); off += (size_t)B_SZ*NN*CP/2;
  half_t* pTl = (half_t*)(wsf + off); off += (size_t)B_SZ*NN*CP/2;
  half_t* gF  = (half_t*)(wsf + off); off += (size_t)B_SZ*CP*NN/2;
  float*  yp  = wsf + off; off += (size_t)KSL * CP * NN;               // 33.5MB
  float*  y   = wsf + off; off += (size_t)B_SZ * CP * NN;
  float*  pmax= wsf + off; off += (size_t)NT * NN;
  float*  psum= wsf + off; off += (size_t)NT * NN;
  float*  corr= wsf + off; off += (size_t)NT * NN;
  float*  meanb = wsf + off; off += CIN;
  float*  rstdb = wsf + off; off += CIN;
  float*  z = (float*)ST;   // alias: ST dead after the batch loop

  tpg_gemm<<<dim3(64, 3, B_SZ), 256, 0, stream>>>(Wt, Wp, Wg, x,
                                                  tTh, tTl, pTh, pTl, gF);

  for (int b = 0; b < B_SZ; ++b){
    s_gemm    <<<dim3(32, 32), 256, 0, stream>>>(tTh, tTl, pTh, pTl,
                                                 ST, pmax, psum, b);
    merge_corr<<<dim3(16),     256, 0, stream>>>(pmax, psum, corr);
    y_gemm    <<<dim3(32, KSL),256, 0, stream>>>(gF, ST, corr, yp, b);
    fold_y    <<<dim3(512),    256, 0, stream>>>((const float4*)yp,
                                                 (float4*)(y + (size_t)b*CP*NN));
  }

  z_gemm   <<<dim3(64, 2, B_SZ), 256, 0, stream>>>(Wz, y, z);
  bn_stats <<<dim3(CIN), 256, 0, stream>>>(z, meanb, rstdb);
  finalize_k<<<dim3(2048), 256, 0, stream>>>(z, x, meanb, rstdb, gamma, beta, out);
}

// Round 5
// 292.206 us; speedup vs baseline: 2.4407x; 1.1419x over previous
//
#include <hip/hip_runtime.h>
#include <hip/hip_fp16.h>

#define B_SZ 4
#define CIN  256
#define CP   128
#define NN   4096
#define NT   32          // 128-row n-tiles per batch (softmax partials)
#define KSL  8           // k-slices in y_gemm

typedef _Float16 half_t;
typedef _Float16 f16x8 __attribute__((ext_vector_type(8)));
typedef float f32x4 __attribute__((ext_vector_type(4)));

#define GPTR(p) ((const __attribute__((address_space(1))) void*)(p))
#define LPTR(p) ((__attribute__((address_space(3))) void*)(p))

__device__ __forceinline__ float wave_sum64(float v){
  #pragma unroll
  for (int o = 32; o > 0; o >>= 1) v += __shfl_xor(v, o, 64);
  return v;
}

// ---------------- K0a: split W*16 into fp16 hi/lo ---------------------------
__global__ __launch_bounds__(256) void split_w(
    const float* __restrict__ Wt, const float* __restrict__ Wp,
    const float* __restrict__ Wg, half_t* __restrict__ Wh,
    half_t* __restrict__ Wl)
{
  const int sel = blockIdx.x;
  const float* W = (sel == 0) ? Wt : ((sel == 1) ? Wp : Wg);
  half_t* oh = Wh + sel * (CP * CIN);
  half_t* ol = Wl + sel * (CP * CIN);
  #pragma unroll
  for (int i = 0; i < 8; ++i){
    int i4 = blockIdx.y * 2048 + threadIdx.x + i * 256;
    float4 v = ((const float4*)W)[i4];
    v.x *= 16.f; v.y *= 16.f; v.z *= 16.f; v.w *= 16.f;
    union { half_t h[4]; uint2 u; } hh, ll;
    hh.h[0] = (half_t)v.x; ll.h[0] = (half_t)(v.x - (float)hh.h[0]);
    hh.h[1] = (half_t)v.y; ll.h[1] = (half_t)(v.y - (float)hh.h[1]);
    hh.h[2] = (half_t)v.z; ll.h[2] = (half_t)(v.z - (float)hh.h[2]);
    hh.h[3] = (half_t)v.w; ll.h[3] = (half_t)(v.w - (float)hh.h[3]);
    *(uint2*)(oh + i4 * 4) = hh.u;
    *(uint2*)(ol + i4 * 4) = ll.u;
  }
}

// ---------------- K0b: transpose-split x -> xT hi/lo [b][n][c] --------------
__global__ __launch_bounds__(256) void split_x(
    const float* __restrict__ x, half_t* __restrict__ xTh,
    half_t* __restrict__ xTl)
{
  const int b  = blockIdx.z;
  const int c0 = blockIdx.y * 64;
  const int n0 = blockIdx.x * 64;
  __shared__ float lds[64][68];
  const int tid = threadIdx.x;
  #pragma unroll
  for (int i = 0; i < 4; ++i){
    int idx = tid + i * 256;
    int cr = idx >> 4, nq = idx & 15;
    float4 v = *(const float4*)(x + ((size_t)b * CIN + c0 + cr) * NN + n0 + nq * 4);
    *(float4*)&lds[cr][nq * 4] = v;
  }
  __syncthreads();
  #pragma unroll
  for (int i = 0; i < 8; ++i){
    int idx = tid + i * 256;
    int nl = idx >> 5;
    int cp = (idx & 31) * 2;
    float v0 = lds[cp][nl], v1 = lds[cp + 1][nl];
    half_t h0 = (half_t)v0, h1 = (half_t)v1;
    half_t l0 = (half_t)(v0 - (float)h0), l1 = (half_t)(v1 - (float)h1);
    union { half_t h[2]; unsigned int u; } ph, pl;
    ph.h[0] = h0; ph.h[1] = h1;
    pl.h[0] = l0; pl.h[1] = l1;
    size_t o = ((size_t)b * NN + n0 + nl) * CIN + c0 + cp;
    *(unsigned int*)(xTh + o) = ph.u;
    *(unsigned int*)(xTl + o) = pl.u;
  }
}

// ---------------- K1: t/p/g via fp16 3-slab MFMA ----------------------------
// D[o][n] = sum_c W16[o][c] * x[c][n] / 16.  A = W split, B = xT split.
// sel 0 -> tT hi/lo ([b][n][CP]), sel 1 -> pT hi/lo, sel 2 -> gF [b][CP][NN]
__global__ __launch_bounds__(256) void tpg_gemm(
    const half_t* __restrict__ Wh, const half_t* __restrict__ Wl,
    const half_t* __restrict__ xTh, const half_t* __restrict__ xTl,
    half_t* __restrict__ tTh, half_t* __restrict__ tTl,
    half_t* __restrict__ pTh, half_t* __restrict__ pTl,
    half_t* __restrict__ gF)
{
  const int b   = blockIdx.z;
  const int sel = blockIdx.y;
  const int n0  = blockIdx.x * 64;
  const half_t* Ah_g = Wh + sel * (CP * CIN);
  const half_t* Al_g = Wl + sel * (CP * CIN);
  const half_t* Bh_g = xTh + ((size_t)b * NN + n0) * CIN;
  const half_t* Bl_g = xTl + ((size_t)b * NN + n0) * CIN;

  __shared__ half_t lds[24576];   // Ah 0 | Al 8192 | Bh 16384 | Bl 20480 (48KB)
  const int tid = threadIdx.x;
  const int wid = tid >> 6, lane = tid & 63;
  const int wo = wid >> 1, wn = wid & 1;
  const int lr = lane & 15, lq = lane >> 4;

  f32x4 acc[4][2];
  #pragma unroll
  for (int i = 0; i < 4; ++i)
    #pragma unroll
    for (int j = 0; j < 2; ++j) acc[i][j] = (f32x4){0.f,0.f,0.f,0.f};

  #pragma unroll 1
  for (int kc = 0; kc < CIN; kc += 64){
    #pragma unroll
    for (int it = 0; it < 4; ++it){
      int seg = wid * 4 + it;                  // 0..15
      int row = seg * 8 + (lane >> 3);         // 0..127
      int us  = (lane & 7) ^ (row & 7);
      size_t go = (size_t)row * CIN + kc + us * 8;
      __builtin_amdgcn_global_load_lds(GPTR(Ah_g + go), LPTR(lds + seg*512), 16, 0, 0);
      __builtin_amdgcn_global_load_lds(GPTR(Al_g + go), LPTR(lds + 8192 + seg*512), 16, 0, 0);
    }
    #pragma unroll
    for (int it = 0; it < 2; ++it){
      int seg = wid * 2 + it;                  // 0..7
      int row = seg * 8 + (lane >> 3);         // 0..63
      int us  = (lane & 7) ^ (row & 7);
      size_t go = (size_t)row * CIN + kc + us * 8;
      __builtin_amdgcn_global_load_lds(GPTR(Bh_g + go), LPTR(lds + 16384 + seg*512), 16, 0, 0);
      __builtin_amdgcn_global_load_lds(GPTR(Bl_g + go), LPTR(lds + 20480 + seg*512), 16, 0, 0);
    }
    asm volatile("s_waitcnt vmcnt(0)" ::: "memory");
    __syncthreads();

    #pragma unroll
    for (int kk = 0; kk < 2; ++kk){
      f16x8 ah[4], al4[4], bh[2], bl[2];
      #pragma unroll
      for (int f = 0; f < 4; ++f){
        int rA = wo * 64 + f * 16 + lr;
        int cA = (kk*32 + lq*8) ^ ((rA & 7) * 8);
        ah[f]  = *(const f16x8*)(lds + rA * 64 + cA);
        al4[f] = *(const f16x8*)(lds + 8192 + rA * 64 + cA);
      }
      #pragma unroll
      for (int f = 0; f < 2; ++f){
        int rB = wn * 32 + f * 16 + lr;
        int cB = (kk*32 + lq*8) ^ ((rB & 7) * 8);
        bh[f] = *(const f16x8*)(lds + 16384 + rB * 64 + cB);
        bl[f] = *(const f16x8*)(lds + 20480 + rB * 64 + cB);
      }
      #pragma unroll
      for (int fo = 0; fo < 4; ++fo)
        #pragma unroll
        for (int fn = 0; fn < 2; ++fn){
          acc[fo][fn] = __builtin_amdgcn_mfma_f32_16x16x32_f16(ah[fo],  bh[fn], acc[fo][fn], 0,0,0);
          acc[fo][fn] = __builtin_amdgcn_mfma_f32_16x16x32_f16(al4[fo], bh[fn], acc[fo][fn], 0,0,0);
          acc[fo][fn] = __builtin_amdgcn_mfma_f32_16x16x32_f16(ah[fo],  bl[fn], acc[fo][fn], 0,0,0);
        }
    }
    __syncthreads();
  }

  if (sel < 2){
    half_t* Ohi = ((sel == 0) ? tTh : pTh) + (size_t)b * NN * CP;
    half_t* Olo = ((sel == 0) ? tTl : pTl) + (size_t)b * NN * CP;
    float (*ldsT)[132] = (float (*)[132])lds;   // [64 n][128 o] padded, 33.8KB
    #pragma unroll
    for (int fo = 0; fo < 4; ++fo)
      #pragma unroll
      for (int fn = 0; fn < 2; ++fn)
        #pragma unroll
        for (int r = 0; r < 4; ++r){
          int n = wn * 32 + fn * 16 + lr;
          int o = wo * 64 + fo * 16 + lq * 4 + r;
          ldsT[n][o] = acc[fo][fn][r] * 0.0625f;
        }
    __syncthreads();
    #pragma unroll
    for (int it = 0; it < 16; ++it){
      int idx = tid + it * 256;                // 4096 pair-units
      int nl = idx >> 6;                       // 0..63
      int cp = (idx & 63) * 2;                 // 0..126
      float v0 = ldsT[nl][cp], v1 = ldsT[nl][cp + 1];
      half_t h0 = (half_t)v0, h1 = (half_t)v1;
      half_t l0 = (half_t)(v0 - (float)h0), l1 = (half_t)(v1 - (float)h1);
      union { half_t h[2]; unsigned int u; } ph, pl;
      ph.h[0] = h0; ph.h[1] = h1;
      pl.h[0] = l0; pl.h[1] = l1;
      *(unsigned int*)(Ohi + (size_t)(n0 + nl) * CP + cp) = ph.u;
      *(unsigned int*)(Olo + (size_t)(n0 + nl) * CP + cp) = pl.u;
    }
  } else {
    half_t* G = gF + (size_t)b * CP * NN;
    #pragma unroll
    for (int fo = 0; fo < 4; ++fo)
      #pragma unroll
      for (int r = 0; r < 4; ++r){
        int o = wo * 64 + fo * 16 + lq * 4 + r;
        #pragma unroll
        for (int fn = 0; fn < 2; ++fn){
          int n = n0 + wn * 32 + fn * 16 + lr;
          G[(size_t)o * NN + n] = (half_t)(acc[fo][fn][r] * 0.0625f);
        }
      }
  }
}

// ---------------- K2: S^T tile + fused col-stats + E(fp16) store ------------
__global__ __launch_bounds__(256) void s_gemm(
    const half_t* __restrict__ tTh, const half_t* __restrict__ tTl,
    const half_t* __restrict__ pTh, const half_t* __restrict__ pTl,
    half_t* __restrict__ ST, float* __restrict__ pmax,
    float* __restrict__ psum, int b)
{
  const int m0 = blockIdx.x * 128;
  const int n0 = blockIdx.y * 128;
  const size_t tb = (size_t)b * NN * CP;
  __shared__ half_t lds[4 * 128 * 64];       // Ah | Al | Bh | Bl, 64 KB
  const int tid = threadIdx.x;
  const int wid = tid >> 6, lane = tid & 63;
  const int wn = wid >> 1, wm = wid & 1;
  const int lr = lane & 15, lq = lane >> 4;

  f32x4 acc[4][4];
  #pragma unroll
  for (int i = 0; i < 4; ++i)
    #pragma unroll
    for (int j = 0; j < 4; ++j) acc[i][j] = (f32x4){0.f,0.f,0.f,0.f};

  const half_t* baseA_h = tTh + tb + (size_t)n0 * CP;
  const half_t* baseA_l = tTl + tb + (size_t)n0 * CP;
  const half_t* baseB_h = pTh + tb + (size_t)m0 * CP;
  const half_t* baseB_l = pTl + tb + (size_t)m0 * CP;

  #pragma unroll 1
  for (int kc = 0; kc < CP; kc += 64){
    #pragma unroll
    for (int it = 0; it < 4; ++it){
      int seg = wid * 4 + it;
      int row = seg * 8 + (lane >> 3);
      int us  = (lane & 7) ^ (row & 7);
      size_t go = (size_t)row * CP + kc + us * 8;
      __builtin_amdgcn_global_load_lds(GPTR(baseA_h + go), LPTR(lds + seg*512), 16, 0, 0);
      __builtin_amdgcn_global_load_lds(GPTR(baseA_l + go), LPTR(lds + 8192 + seg*512), 16, 0, 0);
      __builtin_amdgcn_global_load_lds(GPTR(baseB_h + go), LPTR(lds + 16384 + seg*512), 16, 0, 0);
      __builtin_amdgcn_global_load_lds(GPTR(baseB_l + go), LPTR(lds + 24576 + seg*512), 16, 0, 0);
    }
    asm volatile("s_waitcnt vmcnt(0)" ::: "memory");
    __syncthreads();

    #pragma unroll
    for (int kk = 0; kk < 2; ++kk){
      f16x8 ah[4], al[4], bh[4], bl[4];
      #pragma unroll
      for (int f = 0; f < 4; ++f){
        int rA = wn*64 + f*16 + lr;
        int cA = (kk*32 + lq*8) ^ ((rA & 7) * 8);
        ah[f] = *(const f16x8*)(lds + rA*64 + cA);
        al[f] = *(const f16x8*)(lds + 8192 + rA*64 + cA);
        int rB = wm*64 + f*16 + lr;
        int cB = (kk*32 + lq*8) ^ ((rB & 7) * 8);
        bh[f] = *(const f16x8*)(lds + 16384 + rB*64 + cB);
        bl[f] = *(const f16x8*)(lds + 24576 + rB*64 + cB);
      }
      #pragma unroll
      for (int fn = 0; fn < 4; ++fn)
        #pragma unroll
        for (int fm = 0; fm < 4; ++fm){
          acc[fn][fm] = __builtin_amdgcn_mfma_f32_16x16x32_f16(ah[fn], bh[fm], acc[fn][fm], 0,0,0);
          acc[fn][fm] = __builtin_amdgcn_mfma_f32_16x16x32_f16(al[fn], bh[fm], acc[fn][fm], 0,0,0);
          acc[fn][fm] = __builtin_amdgcn_mfma_f32_16x16x32_f16(ah[fn], bl[fm], acc[fn][fm], 0,0,0);
        }
    }
    __syncthreads();
  }

  // ---- fused column-stats epilogue (stats over n per column m) ----
  float* red  = (float*)lds;
  float* red2 = (float*)lds + 256;

  float cmax[4];
  #pragma unroll
  for (int fm = 0; fm < 4; ++fm){
    float t = -3.0e38f;
    #pragma unroll
    for (int fn = 0; fn < 4; ++fn)
      #pragma unroll
      for (int r = 0; r < 4; ++r) t = fmaxf(t, acc[fn][fm][r]);
    t = fmaxf(t, __shfl_xor(t, 16, 64));
    t = fmaxf(t, __shfl_xor(t, 32, 64));
    cmax[fm] = t;
  }
  if (lq == 0){
    #pragma unroll
    for (int fm = 0; fm < 4; ++fm) red[(wid*4+fm)*16 + lr] = cmax[fm];
  }
  __syncthreads();
  #pragma unroll
  for (int fm = 0; fm < 4; ++fm)
    cmax[fm] = fmaxf(red[((wm)*4+fm)*16 + lr], red[((2+wm)*4+fm)*16 + lr]);

  float csum[4] = {0.f, 0.f, 0.f, 0.f};
  #pragma unroll
  for (int fn = 0; fn < 4; ++fn)
    #pragma unroll
    for (int r = 0; r < 4; ++r){
      int n = n0 + wn*64 + fn*16 + lq*4 + r;
      half_t* dst = ST + (size_t)n * NN + m0 + wm*64;
      #pragma unroll
      for (int fm = 0; fm < 4; ++fm){
        float e = __expf(acc[fn][fm][r] - cmax[fm]);
        csum[fm] += e;
        dst[fm*16 + lr] = (half_t)e;
      }
    }
  #pragma unroll
  for (int fm = 0; fm < 4; ++fm){
    csum[fm] += __shfl_xor(csum[fm], 16, 64);
    csum[fm] += __shfl_xor(csum[fm], 32, 64);
  }
  __syncthreads();
  if (lq == 0){
    #pragma unroll
    for (int fm = 0; fm < 4; ++fm) red2[(wid*4+fm)*16 + lr] = csum[fm];
  }
  __syncthreads();
  if (wn == 0 && lq == 0){
    #pragma unroll
    for (int fm = 0; fm < 4; ++fm){
      int m = m0 + wm*64 + fm*16 + lr;
      pmax[(size_t)blockIdx.y * NN + m] = cmax[fm];
      psum[(size_t)blockIdx.y * NN + m] = red2[((wm)*4+fm)*16 + lr]
                                        + red2[((2+wm)*4+fm)*16 + lr];
    }
  }
}

// ---------------- K3: merge tile partials -> corr[nt][m] --------------------
__global__ __launch_bounds__(256) void merge_corr(
    const float* __restrict__ pmax, const float* __restrict__ psum,
    float* __restrict__ corr)
{
  const int m = blockIdx.x * 256 + threadIdx.x;
  float pm[NT];
  float mx = -3.0e38f;
  #pragma unroll
  for (int nt = 0; nt < NT; ++nt){
    pm[nt] = pmax[(size_t)nt * NN + m];
    mx = fmaxf(mx, pm[nt]);
  }
  float den = 0.f;
  #pragma unroll
  for (int nt = 0; nt < NT; ++nt){
    pm[nt] = __expf(pm[nt] - mx);
    den += psum[(size_t)nt * NN + m] * pm[nt];
  }
  const float r = 1.f / den;
  #pragma unroll
  for (int nt = 0; nt < NT; ++nt)
    corr[(size_t)nt * NN + m] = pm[nt] * r;
}

// ---------------- K4: yp[ks][c][n] = sum_m g[c][m] * (E[n][m]*corr) ---------
// 128c x 64n tile, K = 512 per slice (KSL=8).
__global__ __launch_bounds__(256) void y_gemm(
    const half_t* __restrict__ gF, const half_t* __restrict__ ST,
    const float* __restrict__ corr, float* __restrict__ yp, int b)
{
  const int n0 = blockIdx.x * 64;
  const int nt = blockIdx.x >> 1;
  const int ks = blockIdx.y;
  const half_t* G = gF + (size_t)b * CP * NN;
  __shared__ half_t As[128*64];   // g[c][m-chunk] 16KB
  __shared__ half_t Bs[64*64];    // E'[n][m-chunk] 8KB
  const int tid = threadIdx.x;
  const int wid = tid >> 6, lane = tid & 63;
  const int wc = wid >> 1, wn = wid & 1;
  const int lr = lane & 15, lq = lane >> 4;

  f32x4 acc[4][2];
  #pragma unroll
  for (int i = 0; i < 4; ++i)
    #pragma unroll
    for (int j = 0; j < 2; ++j) acc[i][j] = (f32x4){0.f,0.f,0.f,0.f};

  #pragma unroll 1
  for (int st = 0; st < 8; ++st){
    const int mc = ks * 512 + st * 64;
    #pragma unroll
    for (int it = 0; it < 4; ++it){
      int seg = wid * 4 + it;
      int row = seg * 8 + (lane >> 3);
      int us  = (lane & 7) ^ (row & 7);
      __builtin_amdgcn_global_load_lds(GPTR(G + (size_t)row * NN + mc + us*8),
                                       LPTR(As + seg*512), 16, 0, 0);
    }
    #pragma unroll
    for (int i = 0; i < 4; ++i){
      int idx = tid + i * 256;             // 1024 uint2 units
      int r = idx >> 4;                    // n row 0..63
      int q = idx & 15;                    // m quad
      int mm = mc + q * 4;
      union { half_t h[4]; uint2 u2; } ev, eo;
      ev.u2 = *(const uint2*)(ST + (size_t)(n0 + r) * NN + mm);
      float4 cr = *(const float4*)(corr + (size_t)nt * NN + mm);
      eo.h[0] = (half_t)((float)ev.h[0] * cr.x);
      eo.h[1] = (half_t)((float)ev.h[1] * cr.y);
      eo.h[2] = (half_t)((float)ev.h[2] * cr.z);
      eo.h[3] = (half_t)((float)ev.h[3] * cr.w);
      int c4 = (q * 4) ^ ((r & 7) * 8);
      *(uint2*)(Bs + r * 64 + c4) = eo.u2;
    }
    asm volatile("s_waitcnt vmcnt(0)" ::: "memory");
    __syncthreads();

    #pragma unroll
    for (int kk = 0; kk < 2; ++kk){
      f16x8 af[4], bf[2];
      #pragma unroll
      for (int f = 0; f < 4; ++f){
        int rA = wc*64 + f*16 + lr;
        af[f] = *(const f16x8*)(As + rA*64 + ((kk*32 + lq*8) ^ ((rA & 7)*8)));
      }
      #pragma unroll
      for (int f = 0; f < 2; ++f){
        int rB = wn*32 + f*16 + lr;
        bf[f] = *(const f16x8*)(Bs + rB*64 + ((kk*32 + lq*8) ^ ((rB & 7)*8)));
      }
      #pragma unroll
      for (int fc = 0; fc < 4; ++fc)
        #pragma unroll
        for (int fn = 0; fn < 2; ++fn)
          acc[fc][fn] = __builtin_amdgcn_mfma_f32_16x16x32_f16(af[fc], bf[fn], acc[fc][fn], 0,0,0);
    }
    __syncthreads();
  }
  #pragma unroll
  for (int fc = 0; fc < 4; ++fc)
    #pragma unroll
    for (int r = 0; r < 4; ++r){
      int c = wc*64 + fc*16 + lq*4 + r;
      float* dst = yp + ((size_t)ks * CP + c) * NN + n0;
      #pragma unroll
      for (int fn = 0; fn < 2; ++fn) dst[wn*32 + fn*16 + lr] = acc[fc][fn][r];
    }
}

// ---------------- K4b: fold KSL partials into y[b] --------------------------
__global__ __launch_bounds__(256) void fold_y(
    const float4* __restrict__ yp, float4* __restrict__ dst)
{
  const int i = blockIdx.x * 256 + threadIdx.x;   // 512*256 = CP*NN/4
  float4 a = yp[i];
  #pragma unroll
  for (int s = 1; s < KSL; ++s){
    float4 v = yp[(size_t)s * (CP*NN/4) + i];
    a.x += v.x; a.y += v.y; a.z += v.z; a.w += v.w;
  }
  dst[i] = a;
}

// ---------------- K5: z = Wz @ y (fp32) -------------------------------------
__global__ __launch_bounds__(256) void z_gemm(
    const float* __restrict__ Wz, const float* __restrict__ y,
    float* __restrict__ z)
{
  const int b  = blockIdx.z;
  const int o0 = blockIdx.y * 128;
  const int n0 = blockIdx.x * 64;
  const float* yb = y + (size_t)b * CP * NN;
  float* zb = z + (size_t)b * CIN * NN;

  __shared__ float a_s[32][132];
  __shared__ float b_s[32][64];

  const int tid = threadIdx.x;
  const int tx = tid & 15, ty = tid >> 4;

  float acc[2][4][4];
  #pragma unroll
  for (int qa = 0; qa < 2; ++qa)
    #pragma unroll
    for (int i = 0; i < 4; ++i)
      #pragma unroll
      for (int j = 0; j < 4; ++j) acc[qa][i][j] = 0.f;

  for (int k0 = 0; k0 < CP; k0 += 32){
    #pragma unroll
    for (int i = 0; i < 4; ++i){
      int f4i = tid + i * 256;
      int c  = f4i >> 3;
      int k4 = f4i & 7;
      float4 w = *(const float4*)(Wz + (size_t)(o0 + c) * CP + k0 + k4 * 4);
      a_s[k4*4+0][c] = w.x;
      a_s[k4*4+1][c] = w.y;
      a_s[k4*4+2][c] = w.z;
      a_s[k4*4+3][c] = w.w;
    }
    #pragma unroll
    for (int i = 0; i < 2; ++i){
      int f4i = tid + i * 256;
      int kk = f4i >> 4;
      int n4 = f4i & 15;
      *(float4*)&b_s[kk][n4*4] =
          *(const float4*)(yb + (size_t)(k0 + kk) * NN + n0 + n4 * 4);
    }
    __syncthreads();
    #pragma unroll
    for (int kk = 0; kk < 32; ++kk){
      float af[8], bf[4];
      *(float4*)&af[0] = *(const float4*)&a_s[kk][ty*4];
      *(float4*)&af[4] = *(const float4*)&a_s[kk][ty*4+64];
      *(float4*)&bf[0] = *(const float4*)&b_s[kk][tx*4];
      #pragma unroll
      for (int qa = 0; qa < 2; ++qa)
        #pragma unroll
        for (int i = 0; i < 4; ++i)
          #pragma unroll
          for (int j = 0; j < 4; ++j)
            acc[qa][i][j] = fmaf(af[qa*4+i], bf[j], acc[qa][i][j]);
    }
    __syncthreads();
  }
  #pragma unroll
  for (int qa = 0; qa < 2; ++qa)
    #pragma unroll
    for (int i = 0; i < 4; ++i){
      const int row = o0 + qa*64 + ty*4 + i;
      float4 v = make_float4(acc[qa][i][0], acc[qa][i][1],
                             acc[qa][i][2], acc[qa][i][3]);
      *(float4*)(zb + (size_t)row * NN + n0 + tx*4) = v;
    }
}

// ---------------- K6: BatchNorm batch stats ---------------------------------
__global__ __launch_bounds__(256) void bn_stats(
    const float* __restrict__ z, float* __restrict__ mean,
    float* __restrict__ rstd)
{
  const int c = blockIdx.x;
  const int tid = threadIdx.x;
  float s = 0.f, s2 = 0.f;
  for (int b = 0; b < B_SZ; ++b){
    const float4* row = (const float4*)(z + ((size_t)b * CIN + c) * NN);
    #pragma unroll
    for (int i = 0; i < 4; ++i){
      float4 v = row[tid + i*256];
      s  += v.x + v.y + v.z + v.w;
      s2 += v.x*v.x + v.y*v.y + v.z*v.z + v.w*v.w;
    }
  }
  s  = wave_sum64(s);
  s2 = wave_sum64(s2);
  __shared__ float rs[4];
  __shared__ float rq[4];
  const int wid = tid >> 6, lane = tid & 63;
  if (lane == 0){ rs[wid] = s; rq[wid] = s2; }
  __syncthreads();
  if (tid == 0){
    const float S1 = rs[0]+rs[1]+rs[2]+rs[3];
    const float S2 = rq[0]+rq[1]+rq[2]+rq[3];
    const float inv = 1.f / (float)(B_SZ * NN);
    const float m = S1 * inv;
    const float var = S2 * inv - m * m;
    mean[c] = m;
    rstd[c] = 1.f / sqrtf(var + 1e-5f);
  }
}

// ---------------- K7: out = (z-mean)*rstd*gamma + beta + x ------------------
__global__ __launch_bounds__(256) void finalize_k(
    const float* __restrict__ z, const float* __restrict__ x,
    const float* __restrict__ mean, const float* __restrict__ rstd,
    const float* __restrict__ gamma, const float* __restrict__ beta,
    float* __restrict__ out)
{
  const int total = B_SZ * CIN * NN / 4;
  for (int i = blockIdx.x * blockDim.x + threadIdx.x; i < total;
       i += gridDim.x * blockDim.x){
    const int c = (i >> 10) & (CIN - 1);
    float4 zv = ((const float4*)z)[i];
    float4 xv = ((const float4*)x)[i];
    const float m = mean[c], r = rstd[c], ga = gamma[c], be = beta[c];
    float4 o;
    o.x = (zv.x - m) * r * ga + be + xv.x;
    o.y = (zv.y - m) * r * ga + be + xv.y;
    o.z = (zv.z - m) * r * ga + be + xv.z;
    o.w = (zv.w - m) * r * ga + be + xv.w;
    ((float4*)out)[i] = o;
  }
}

// ---------------- launcher --------------------------------------------------
extern "C" void kernel_launch(void* const* d_in, const int* in_sizes, int n_in,
                              void* d_out, int out_size, void* d_ws, size_t ws_size,
                              hipStream_t stream)
{
  const float* x     = (const float*)d_in[0];
  const float* Wt    = (const float*)d_in[1];
  const float* Wp    = (const float*)d_in[2];
  const float* Wg    = (const float*)d_in[3];
  const float* Wz    = (const float*)d_in[4];
  const float* gamma = (const float*)d_in[5];
  const float* beta  = (const float*)d_in[6];
  float* out = (float*)d_out;

  float* wsf = (float*)d_ws;
  size_t off = 0;
  half_t* ST  = (half_t*)(wsf + off); off += (size_t)NN * NN / 2;      // 33.5MB
  half_t* tTh = (half_t*)(wsf + off); off += (size_t)B_SZ*NN*CP/2;
  half_t* tTl = (half_t*)(wsf + off); off += (size_t)B_SZ*NN*CP/2;
  half_t* pTh = (half_t*)(wsf + off); off += (size_t)B_SZ*NN*CP/2;
  half_t* pTl = (half_t*)(wsf + off); off += (size_t)B_SZ*NN*CP/2;
  half_t* gF  = (half_t*)(wsf + off); off += (size_t)B_SZ*CP*NN/2;
  half_t* xTh = (half_t*)(wsf + off); off += (size_t)B_SZ*NN*CIN/2;
  half_t* xTl = (half_t*)(wsf + off); off += (size_t)B_SZ*NN*CIN/2;
  half_t* Wh  = (half_t*)(wsf + off); off += (size_t)3*CP*CIN/2;
  half_t* Wl  = (half_t*)(wsf + off); off += (size_t)3*CP*CIN/2;
  float*  yp  = wsf + off; off += (size_t)KSL * CP * NN;               // 16.8MB
  float*  y   = wsf + off; off += (size_t)B_SZ * CP * NN;
  float*  pmax= wsf + off; off += (size_t)NT * NN;
  float*  psum= wsf + off; off += (size_t)NT * NN;
  float*  corr= wsf + off; off += (size_t)NT * NN;
  float*  meanb = wsf + off; off += CIN;
  float*  rstdb = wsf + off; off += CIN;
  float*  z = (float*)ST;   // alias: ST dead after the batch loop

  split_w <<<dim3(3, 4),        256, 0, stream>>>(Wt, Wp, Wg, Wh, Wl);
  split_x <<<dim3(64, 4, B_SZ), 256, 0, stream>>>(x, xTh, xTl);
  tpg_gemm<<<dim3(64, 3, B_SZ), 256, 0, stream>>>(Wh, Wl, xTh, xTl,
                                                  tTh, tTl, pTh, pTl, gF);

  for (int b = 0; b < B_SZ; ++b){
    s_gemm    <<<dim3(32, 32), 256, 0, stream>>>(tTh, tTl, pTh, pTl,
                                                 ST, pmax, psum, b);
    merge_corr<<<dim3(16),     256, 0, stream>>>(pmax, psum, corr);
    y_gemm    <<<dim3(64, KSL),256, 0, stream>>>(gF, ST, corr, yp, b);
    fold_y    <<<dim3(512),    256, 0, stream>>>((const float4*)yp,
                                                 (float4*)(y + (size_t)b*CP*NN));
  }

  z_gemm   <<<dim3(64, 2, B_SZ), 256, 0, stream>>>(Wz, y, z);
  bn_stats <<<dim3(CIN), 256, 0, stream>>>(z, meanb, rstdb);
  finalize_k<<<dim3(2048), 256, 0, stream>>>(z, x, meanb, rstdb, gamma, beta, out);
}

// Round 6
// 252.720 us; speedup vs baseline: 2.8220x; 1.1562x over previous
//
#include <hip/hip_runtime.h>
#include <hip/hip_fp16.h>

#define B_SZ 4
#define CIN  256
#define CP   128
#define NN   4096
#define NT   32          // 128-row n-tiles per batch (softmax partials)
#define KSL  4           // k-slices in y_gemm (K=1024 each)

typedef _Float16 half_t;
typedef _Float16 f16x8 __attribute__((ext_vector_type(8)));
typedef float f32x4 __attribute__((ext_vector_type(4)));

#define GPTR(p) ((const __attribute__((address_space(1))) void*)(p))
#define LPTR(p) ((__attribute__((address_space(3))) void*)(p))

__device__ __forceinline__ float wave_sum64(float v){
  #pragma unroll
  for (int o = 32; o > 0; o >>= 1) v += __shfl_xor(v, o, 64);
  return v;
}

// ---------------- K0a: split W*16 into fp16 hi/lo ---------------------------
__global__ __launch_bounds__(256) void split_w(
    const float* __restrict__ Wt, const float* __restrict__ Wp,
    const float* __restrict__ Wg, half_t* __restrict__ Wh,
    half_t* __restrict__ Wl)
{
  const int sel = blockIdx.x;
  const float* W = (sel == 0) ? Wt : ((sel == 1) ? Wp : Wg);
  half_t* oh = Wh + sel * (CP * CIN);
  half_t* ol = Wl + sel * (CP * CIN);
  #pragma unroll
  for (int i = 0; i < 8; ++i){
    int i4 = blockIdx.y * 2048 + threadIdx.x + i * 256;
    float4 v = ((const float4*)W)[i4];
    v.x *= 16.f; v.y *= 16.f; v.z *= 16.f; v.w *= 16.f;
    union { half_t h[4]; uint2 u; } hh, ll;
    hh.h[0] = (half_t)v.x; ll.h[0] = (half_t)(v.x - (float)hh.h[0]);
    hh.h[1] = (half_t)v.y; ll.h[1] = (half_t)(v.y - (float)hh.h[1]);
    hh.h[2] = (half_t)v.z; ll.h[2] = (half_t)(v.z - (float)hh.h[2]);
    hh.h[3] = (half_t)v.w; ll.h[3] = (half_t)(v.w - (float)hh.h[3]);
    *(uint2*)(oh + i4 * 4) = hh.u;
    *(uint2*)(ol + i4 * 4) = ll.u;
  }
}

// ---------------- K0b: transpose-split x -> xT hi/lo [b][n][c] --------------
__global__ __launch_bounds__(256) void split_x(
    const float* __restrict__ x, half_t* __restrict__ xTh,
    half_t* __restrict__ xTl)
{
  const int b  = blockIdx.z;
  const int c0 = blockIdx.y * 64;
  const int n0 = blockIdx.x * 64;
  __shared__ float lds[64][68];
  const int tid = threadIdx.x;
  #pragma unroll
  for (int i = 0; i < 4; ++i){
    int idx = tid + i * 256;
    int cr = idx >> 4, nq = idx & 15;
    float4 v = *(const float4*)(x + ((size_t)b * CIN + c0 + cr) * NN + n0 + nq * 4);
    *(float4*)&lds[cr][nq * 4] = v;
  }
  __syncthreads();
  #pragma unroll
  for (int i = 0; i < 8; ++i){
    int idx = tid + i * 256;
    int nl = idx >> 5;
    int cp = (idx & 31) * 2;
    float v0 = lds[cp][nl], v1 = lds[cp + 1][nl];
    half_t h0 = (half_t)v0, h1 = (half_t)v1;
    half_t l0 = (half_t)(v0 - (float)h0), l1 = (half_t)(v1 - (float)h1);
    union { half_t h[2]; unsigned int u; } ph, pl;
    ph.h[0] = h0; ph.h[1] = h1;
    pl.h[0] = l0; pl.h[1] = l1;
    size_t o = ((size_t)b * NN + n0 + nl) * CIN + c0 + cp;
    *(unsigned int*)(xTh + o) = ph.u;
    *(unsigned int*)(xTl + o) = pl.u;
  }
}

// ---------------- K1: t/p/g via fp16 3-slab MFMA ----------------------------
__global__ __launch_bounds__(256) void tpg_gemm(
    const half_t* __restrict__ Wh, const half_t* __restrict__ Wl,
    const half_t* __restrict__ xTh, const half_t* __restrict__ xTl,
    half_t* __restrict__ tTh, half_t* __restrict__ tTl,
    half_t* __restrict__ pTh, half_t* __restrict__ pTl,
    half_t* __restrict__ gF)
{
  const int b   = blockIdx.z;
  const int sel = blockIdx.y;
  const int n0  = blockIdx.x * 64;
  const half_t* Ah_g = Wh + sel * (CP * CIN);
  const half_t* Al_g = Wl + sel * (CP * CIN);
  const half_t* Bh_g = xTh + ((size_t)b * NN + n0) * CIN;
  const half_t* Bl_g = xTl + ((size_t)b * NN + n0) * CIN;

  __shared__ half_t lds[24576];   // Ah 0 | Al 8192 | Bh 16384 | Bl 20480
  const int tid = threadIdx.x;
  const int wid = tid >> 6, lane = tid & 63;
  const int wo = wid >> 1, wn = wid & 1;
  const int lr = lane & 15, lq = lane >> 4;

  f32x4 acc[4][2];
  #pragma unroll
  for (int i = 0; i < 4; ++i)
    #pragma unroll
    for (int j = 0; j < 2; ++j) acc[i][j] = (f32x4){0.f,0.f,0.f,0.f};

  #pragma unroll 1
  for (int kc = 0; kc < CIN; kc += 64){
    #pragma unroll
    for (int it = 0; it < 4; ++it){
      int seg = wid * 4 + it;
      int row = seg * 8 + (lane >> 3);
      int us  = (lane & 7) ^ (row & 7);
      size_t go = (size_t)row * CIN + kc + us * 8;
      __builtin_amdgcn_global_load_lds(GPTR(Ah_g + go), LPTR(lds + seg*512), 16, 0, 0);
      __builtin_amdgcn_global_load_lds(GPTR(Al_g + go), LPTR(lds + 8192 + seg*512), 16, 0, 0);
    }
    #pragma unroll
    for (int it = 0; it < 2; ++it){
      int seg = wid * 2 + it;
      int row = seg * 8 + (lane >> 3);
      int us  = (lane & 7) ^ (row & 7);
      size_t go = (size_t)row * CIN + kc + us * 8;
      __builtin_amdgcn_global_load_lds(GPTR(Bh_g + go), LPTR(lds + 16384 + seg*512), 16, 0, 0);
      __builtin_amdgcn_global_load_lds(GPTR(Bl_g + go), LPTR(lds + 20480 + seg*512), 16, 0, 0);
    }
    asm volatile("s_waitcnt vmcnt(0)" ::: "memory");
    __syncthreads();

    #pragma unroll
    for (int kk = 0; kk < 2; ++kk){
      f16x8 ah[4], al4[4], bh[2], bl[2];
      #pragma unroll
      for (int f = 0; f < 4; ++f){
        int rA = wo * 64 + f * 16 + lr;
        int cA = (kk*32 + lq*8) ^ ((rA & 7) * 8);
        ah[f]  = *(const f16x8*)(lds + rA * 64 + cA);
        al4[f] = *(const f16x8*)(lds + 8192 + rA * 64 + cA);
      }
      #pragma unroll
      for (int f = 0; f < 2; ++f){
        int rB = wn * 32 + f * 16 + lr;
        int cB = (kk*32 + lq*8) ^ ((rB & 7) * 8);
        bh[f] = *(const f16x8*)(lds + 16384 + rB * 64 + cB);
        bl[f] = *(const f16x8*)(lds + 20480 + rB * 64 + cB);
      }
      #pragma unroll
      for (int fo = 0; fo < 4; ++fo)
        #pragma unroll
        for (int fn = 0; fn < 2; ++fn){
          acc[fo][fn] = __builtin_amdgcn_mfma_f32_16x16x32_f16(ah[fo],  bh[fn], acc[fo][fn], 0,0,0);
          acc[fo][fn] = __builtin_amdgcn_mfma_f32_16x16x32_f16(al4[fo], bh[fn], acc[fo][fn], 0,0,0);
          acc[fo][fn] = __builtin_amdgcn_mfma_f32_16x16x32_f16(ah[fo],  bl[fn], acc[fo][fn], 0,0,0);
        }
    }
    __syncthreads();
  }

  if (sel < 2){
    half_t* Ohi = ((sel == 0) ? tTh : pTh) + (size_t)b * NN * CP;
    half_t* Olo = ((sel == 0) ? tTl : pTl) + (size_t)b * NN * CP;
    float (*ldsT)[132] = (float (*)[132])lds;
    #pragma unroll
    for (int fo = 0; fo < 4; ++fo)
      #pragma unroll
      for (int fn = 0; fn < 2; ++fn)
        #pragma unroll
        for (int r = 0; r < 4; ++r){
          int n = wn * 32 + fn * 16 + lr;
          int o = wo * 64 + fo * 16 + lq * 4 + r;
          ldsT[n][o] = acc[fo][fn][r] * 0.0625f;
        }
    __syncthreads();
    #pragma unroll
    for (int it = 0; it < 16; ++it){
      int idx = tid + it * 256;
      int nl = idx >> 6;
      int cp = (idx & 63) * 2;
      float v0 = ldsT[nl][cp], v1 = ldsT[nl][cp + 1];
      half_t h0 = (half_t)v0, h1 = (half_t)v1;
      half_t l0 = (half_t)(v0 - (float)h0), l1 = (half_t)(v1 - (float)h1);
      union { half_t h[2]; unsigned int u; } ph, pl;
      ph.h[0] = h0; ph.h[1] = h1;
      pl.h[0] = l0; pl.h[1] = l1;
      *(unsigned int*)(Ohi + (size_t)(n0 + nl) * CP + cp) = ph.u;
      *(unsigned int*)(Olo + (size_t)(n0 + nl) * CP + cp) = pl.u;
    }
  } else {
    half_t* G = gF + (size_t)b * CP * NN;
    #pragma unroll
    for (int fo = 0; fo < 4; ++fo)
      #pragma unroll
      for (int r = 0; r < 4; ++r){
        int o = wo * 64 + fo * 16 + lq * 4 + r;
        #pragma unroll
        for (int fn = 0; fn < 2; ++fn){
          int n = n0 + wn * 32 + fn * 16 + lr;
          G[(size_t)o * NN + n] = (half_t)(acc[fo][fn][r] * 0.0625f);
        }
      }
  }
}

// ---------------- K2: S^T tile + fused col-stats + E(fp16) store (batched) --
__global__ __launch_bounds__(256) void s_gemm(
    const half_t* __restrict__ tTh, const half_t* __restrict__ tTl,
    const half_t* __restrict__ pTh, const half_t* __restrict__ pTl,
    half_t* __restrict__ ST, float* __restrict__ pmax,
    float* __restrict__ psum)
{
  const int b  = blockIdx.z;
  const int m0 = blockIdx.x * 128;
  const int n0 = blockIdx.y * 128;
  const size_t tb = (size_t)b * NN * CP;
  half_t* STb = ST + (size_t)b * NN * NN;
  __shared__ half_t lds[4 * 128 * 64];       // Ah | Al | Bh | Bl, 64 KB
  const int tid = threadIdx.x;
  const int wid = tid >> 6, lane = tid & 63;
  const int wn = wid >> 1, wm = wid & 1;
  const int lr = lane & 15, lq = lane >> 4;

  f32x4 acc[4][4];
  #pragma unroll
  for (int i = 0; i < 4; ++i)
    #pragma unroll
    for (int j = 0; j < 4; ++j) acc[i][j] = (f32x4){0.f,0.f,0.f,0.f};

  const half_t* baseA_h = tTh + tb + (size_t)n0 * CP;
  const half_t* baseA_l = tTl + tb + (size_t)n0 * CP;
  const half_t* baseB_h = pTh + tb + (size_t)m0 * CP;
  const half_t* baseB_l = pTl + tb + (size_t)m0 * CP;

  #pragma unroll 1
  for (int kc = 0; kc < CP; kc += 64){
    #pragma unroll
    for (int it = 0; it < 4; ++it){
      int seg = wid * 4 + it;
      int row = seg * 8 + (lane >> 3);
      int us  = (lane & 7) ^ (row & 7);
      size_t go = (size_t)row * CP + kc + us * 8;
      __builtin_amdgcn_global_load_lds(GPTR(baseA_h + go), LPTR(lds + seg*512), 16, 0, 0);
      __builtin_amdgcn_global_load_lds(GPTR(baseA_l + go), LPTR(lds + 8192 + seg*512), 16, 0, 0);
      __builtin_amdgcn_global_load_lds(GPTR(baseB_h + go), LPTR(lds + 16384 + seg*512), 16, 0, 0);
      __builtin_amdgcn_global_load_lds(GPTR(baseB_l + go), LPTR(lds + 24576 + seg*512), 16, 0, 0);
    }
    asm volatile("s_waitcnt vmcnt(0)" ::: "memory");
    __syncthreads();

    #pragma unroll
    for (int kk = 0; kk < 2; ++kk){
      f16x8 ah[4], al[4], bh[4], bl[4];
      #pragma unroll
      for (int f = 0; f < 4; ++f){
        int rA = wn*64 + f*16 + lr;
        int cA = (kk*32 + lq*8) ^ ((rA & 7) * 8);
        ah[f] = *(const f16x8*)(lds + rA*64 + cA);
        al[f] = *(const f16x8*)(lds + 8192 + rA*64 + cA);
        int rB = wm*64 + f*16 + lr;
        int cB = (kk*32 + lq*8) ^ ((rB & 7) * 8);
        bh[f] = *(const f16x8*)(lds + 16384 + rB*64 + cB);
        bl[f] = *(const f16x8*)(lds + 24576 + rB*64 + cB);
      }
      #pragma unroll
      for (int fn = 0; fn < 4; ++fn)
        #pragma unroll
        for (int fm = 0; fm < 4; ++fm){
          acc[fn][fm] = __builtin_amdgcn_mfma_f32_16x16x32_f16(ah[fn], bh[fm], acc[fn][fm], 0,0,0);
          acc[fn][fm] = __builtin_amdgcn_mfma_f32_16x16x32_f16(al[fn], bh[fm], acc[fn][fm], 0,0,0);
          acc[fn][fm] = __builtin_amdgcn_mfma_f32_16x16x32_f16(ah[fn], bl[fm], acc[fn][fm], 0,0,0);
        }
    }
    __syncthreads();
  }

  // ---- fused column-stats epilogue ----
  float* red  = (float*)lds;
  float* red2 = (float*)lds + 256;

  float cmax[4];
  #pragma unroll
  for (int fm = 0; fm < 4; ++fm){
    float t = -3.0e38f;
    #pragma unroll
    for (int fn = 0; fn < 4; ++fn)
      #pragma unroll
      for (int r = 0; r < 4; ++r) t = fmaxf(t, acc[fn][fm][r]);
    t = fmaxf(t, __shfl_xor(t, 16, 64));
    t = fmaxf(t, __shfl_xor(t, 32, 64));
    cmax[fm] = t;
  }
  if (lq == 0){
    #pragma unroll
    for (int fm = 0; fm < 4; ++fm) red[(wid*4+fm)*16 + lr] = cmax[fm];
  }
  __syncthreads();
  #pragma unroll
  for (int fm = 0; fm < 4; ++fm)
    cmax[fm] = fmaxf(red[((wm)*4+fm)*16 + lr], red[((2+wm)*4+fm)*16 + lr]);

  float csum[4] = {0.f, 0.f, 0.f, 0.f};
  #pragma unroll
  for (int fn = 0; fn < 4; ++fn)
    #pragma unroll
    for (int r = 0; r < 4; ++r){
      int n = n0 + wn*64 + fn*16 + lq*4 + r;
      half_t* dst = STb + (size_t)n * NN + m0 + wm*64;
      #pragma unroll
      for (int fm = 0; fm < 4; ++fm){
        float e = __expf(acc[fn][fm][r] - cmax[fm]);
        csum[fm] += e;
        dst[fm*16 + lr] = (half_t)e;
      }
    }
  #pragma unroll
  for (int fm = 0; fm < 4; ++fm){
    csum[fm] += __shfl_xor(csum[fm], 16, 64);
    csum[fm] += __shfl_xor(csum[fm], 32, 64);
  }
  __syncthreads();
  if (lq == 0){
    #pragma unroll
    for (int fm = 0; fm < 4; ++fm) red2[(wid*4+fm)*16 + lr] = csum[fm];
  }
  __syncthreads();
  if (wn == 0 && lq == 0){
    #pragma unroll
    for (int fm = 0; fm < 4; ++fm){
      int m = m0 + wm*64 + fm*16 + lr;
      pmax[((size_t)b * NT + blockIdx.y) * NN + m] = cmax[fm];
      psum[((size_t)b * NT + blockIdx.y) * NN + m] = red2[((wm)*4+fm)*16 + lr]
                                                   + red2[((2+wm)*4+fm)*16 + lr];
    }
  }
}

// ---------------- K3: merge tile partials -> corr[b][nt][m] -----------------
__global__ __launch_bounds__(256) void merge_corr(
    const float* __restrict__ pmax, const float* __restrict__ psum,
    float* __restrict__ corr)
{
  const size_t base = (size_t)blockIdx.y * NT * NN;
  const int m = blockIdx.x * 256 + threadIdx.x;
  float pm[NT];
  float mx = -3.0e38f;
  #pragma unroll
  for (int nt = 0; nt < NT; ++nt){
    pm[nt] = pmax[base + (size_t)nt * NN + m];
    mx = fmaxf(mx, pm[nt]);
  }
  float den = 0.f;
  #pragma unroll
  for (int nt = 0; nt < NT; ++nt){
    pm[nt] = __expf(pm[nt] - mx);
    den += psum[base + (size_t)nt * NN + m] * pm[nt];
  }
  const float r = 1.f / den;
  #pragma unroll
  for (int nt = 0; nt < NT; ++nt)
    corr[base + (size_t)nt * NN + m] = pm[nt] * r;
}

// ---------------- K4: yp[b][ks][c][n] = sum_m g[c][m]*(E[n][m]*corr) --------
__global__ __launch_bounds__(256) void y_gemm(
    const half_t* __restrict__ gF, const half_t* __restrict__ ST,
    const float* __restrict__ corr, float* __restrict__ yp)
{
  const int b  = blockIdx.z;
  const int n0 = blockIdx.x * 64;
  const int nt = blockIdx.x >> 1;
  const int ks = blockIdx.y;
  const half_t* G   = gF + (size_t)b * CP * NN;
  const half_t* STb = ST + (size_t)b * NN * NN;
  const float* corb = corr + ((size_t)b * NT + nt) * NN;
  __shared__ half_t As[128*64];
  __shared__ half_t Bs[64*64];
  const int tid = threadIdx.x;
  const int wid = tid >> 6, lane = tid & 63;
  const int wc = wid >> 1, wn = wid & 1;
  const int lr = lane & 15, lq = lane >> 4;

  f32x4 acc[4][2];
  #pragma unroll
  for (int i = 0; i < 4; ++i)
    #pragma unroll
    for (int j = 0; j < 2; ++j) acc[i][j] = (f32x4){0.f,0.f,0.f,0.f};

  #pragma unroll 1
  for (int st = 0; st < 16; ++st){
    const int mc = ks * (NN / KSL) + st * 64;
    #pragma unroll
    for (int it = 0; it < 4; ++it){
      int seg = wid * 4 + it;
      int row = seg * 8 + (lane >> 3);
      int us  = (lane & 7) ^ (row & 7);
      __builtin_amdgcn_global_load_lds(GPTR(G + (size_t)row * NN + mc + us*8),
                                       LPTR(As + seg*512), 16, 0, 0);
    }
    #pragma unroll
    for (int i = 0; i < 4; ++i){
      int idx = tid + i * 256;
      int r = idx >> 4;
      int q = idx & 15;
      int mm = mc + q * 4;
      union { half_t h[4]; uint2 u2; } ev, eo;
      ev.u2 = *(const uint2*)(STb + (size_t)(n0 + r) * NN + mm);
      float4 cr = *(const float4*)(corb + mm);
      eo.h[0] = (half_t)((float)ev.h[0] * cr.x);
      eo.h[1] = (half_t)((float)ev.h[1] * cr.y);
      eo.h[2] = (half_t)((float)ev.h[2] * cr.z);
      eo.h[3] = (half_t)((float)ev.h[3] * cr.w);
      int c4 = (q * 4) ^ ((r & 7) * 8);
      *(uint2*)(Bs + r * 64 + c4) = eo.u2;
    }
    asm volatile("s_waitcnt vmcnt(0)" ::: "memory");
    __syncthreads();

    #pragma unroll
    for (int kk = 0; kk < 2; ++kk){
      f16x8 af[4], bf[2];
      #pragma unroll
      for (int f = 0; f < 4; ++f){
        int rA = wc*64 + f*16 + lr;
        af[f] = *(const f16x8*)(As + rA*64 + ((kk*32 + lq*8) ^ ((rA & 7)*8)));
      }
      #pragma unroll
      for (int f = 0; f < 2; ++f){
        int rB = wn*32 + f*16 + lr;
        bf[f] = *(const f16x8*)(Bs + rB*64 + ((kk*32 + lq*8) ^ ((rB & 7)*8)));
      }
      #pragma unroll
      for (int fc = 0; fc < 4; ++fc)
        #pragma unroll
        for (int fn = 0; fn < 2; ++fn)
          acc[fc][fn] = __builtin_amdgcn_mfma_f32_16x16x32_f16(af[fc], bf[fn], acc[fc][fn], 0,0,0);
    }
    __syncthreads();
  }
  #pragma unroll
  for (int fc = 0; fc < 4; ++fc)
    #pragma unroll
    for (int r = 0; r < 4; ++r){
      int c = wc*64 + fc*16 + lq*4 + r;
      float* dst = yp + (((size_t)b * KSL + ks) * CP + c) * NN + n0;
      #pragma unroll
      for (int fn = 0; fn < 2; ++fn) dst[wn*32 + fn*16 + lr] = acc[fc][fn][r];
    }
}

// ---------------- K5: z = Wz @ y (fp32; sums the KSL partials in staging) ---
__global__ __launch_bounds__(256) void z_gemm(
    const float* __restrict__ Wz, const float* __restrict__ yp,
    float* __restrict__ z)
{
  const int b  = blockIdx.z;
  const int o0 = blockIdx.y * 128;
  const int n0 = blockIdx.x * 64;
  const float* y0 = yp + ((size_t)b * KSL + 0) * CP * NN;
  const float* y1 = yp + ((size_t)b * KSL + 1) * CP * NN;
  const float* y2 = yp + ((size_t)b * KSL + 2) * CP * NN;
  const float* y3 = yp + ((size_t)b * KSL + 3) * CP * NN;
  float* zb = z + (size_t)b * CIN * NN;

  __shared__ float a_s[32][132];
  __shared__ float b_s[32][64];

  const int tid = threadIdx.x;
  const int tx = tid & 15, ty = tid >> 4;

  float acc[2][4][4];
  #pragma unroll
  for (int qa = 0; qa < 2; ++qa)
    #pragma unroll
    for (int i = 0; i < 4; ++i)
      #pragma unroll
      for (int j = 0; j < 4; ++j) acc[qa][i][j] = 0.f;

  for (int k0 = 0; k0 < CP; k0 += 32){
    #pragma unroll
    for (int i = 0; i < 4; ++i){
      int f4i = tid + i * 256;
      int c  = f4i >> 3;
      int k4 = f4i & 7;
      float4 w = *(const float4*)(Wz + (size_t)(o0 + c) * CP + k0 + k4 * 4);
      a_s[k4*4+0][c] = w.x;
      a_s[k4*4+1][c] = w.y;
      a_s[k4*4+2][c] = w.z;
      a_s[k4*4+3][c] = w.w;
    }
    #pragma unroll
    for (int i = 0; i < 2; ++i){
      int f4i = tid + i * 256;
      int kk = f4i >> 4;
      int n4 = f4i & 15;
      const size_t off = (size_t)(k0 + kk) * NN + n0 + n4 * 4;
      float4 v0 = *(const float4*)(y0 + off);
      float4 v1 = *(const float4*)(y1 + off);
      float4 v2 = *(const float4*)(y2 + off);
      float4 v3 = *(const float4*)(y3 + off);
      float4 sv;
      sv.x = v0.x + v1.x + v2.x + v3.x;
      sv.y = v0.y + v1.y + v2.y + v3.y;
      sv.z = v0.z + v1.z + v2.z + v3.z;
      sv.w = v0.w + v1.w + v2.w + v3.w;
      *(float4*)&b_s[kk][n4*4] = sv;
    }
    __syncthreads();
    #pragma unroll
    for (int kk = 0; kk < 32; ++kk){
      float af[8], bf[4];
      *(float4*)&af[0] = *(const float4*)&a_s[kk][ty*4];
      *(float4*)&af[4] = *(const float4*)&a_s[kk][ty*4+64];
      *(float4*)&bf[0] = *(const float4*)&b_s[kk][tx*4];
      #pragma unroll
      for (int qa = 0; qa < 2; ++qa)
        #pragma unroll
        for (int i = 0; i < 4; ++i)
          #pragma unroll
          for (int j = 0; j < 4; ++j)
            acc[qa][i][j] = fmaf(af[qa*4+i], bf[j], acc[qa][i][j]);
    }
    __syncthreads();
  }
  #pragma unroll
  for (int qa = 0; qa < 2; ++qa)
    #pragma unroll
    for (int i = 0; i < 4; ++i){
      const int row = o0 + qa*64 + ty*4 + i;
      float4 v = make_float4(acc[qa][i][0], acc[qa][i][1],
                             acc[qa][i][2], acc[qa][i][3]);
      *(float4*)(zb + (size_t)row * NN + n0 + tx*4) = v;
    }
}

// ---------------- K6: BatchNorm batch stats ---------------------------------
__global__ __launch_bounds__(256) void bn_stats(
    const float* __restrict__ z, float* __restrict__ mean,
    float* __restrict__ rstd)
{
  const int c = blockIdx.x;
  const int tid = threadIdx.x;
  float s = 0.f, s2 = 0.f;
  for (int b = 0; b < B_SZ; ++b){
    const float4* row = (const float4*)(z + ((size_t)b * CIN + c) * NN);
    #pragma unroll
    for (int i = 0; i < 4; ++i){
      float4 v = row[tid + i*256];
      s  += v.x + v.y + v.z + v.w;
      s2 += v.x*v.x + v.y*v.y + v.z*v.z + v.w*v.w;
    }
  }
  s  = wave_sum64(s);
  s2 = wave_sum64(s2);
  __shared__ float rs[4];
  __shared__ float rq[4];
  const int wid = tid >> 6, lane = tid & 63;
  if (lane == 0){ rs[wid] = s; rq[wid] = s2; }
  __syncthreads();
  if (tid == 0){
    const float S1 = rs[0]+rs[1]+rs[2]+rs[3];
    const float S2 = rq[0]+rq[1]+rq[2]+rq[3];
    const float inv = 1.f / (float)(B_SZ * NN);
    const float m = S1 * inv;
    const float var = S2 * inv - m * m;
    mean[c] = m;
    rstd[c] = 1.f / sqrtf(var + 1e-5f);
  }
}

// ---------------- K7: out = (z-mean)*rstd*gamma + beta + x ------------------
__global__ __launch_bounds__(256) void finalize_k(
    const float* __restrict__ z, const float* __restrict__ x,
    const float* __restrict__ mean, const float* __restrict__ rstd,
    const float* __restrict__ gamma, const float* __restrict__ beta,
    float* __restrict__ out)
{
  const int total = B_SZ * CIN * NN / 4;
  for (int i = blockIdx.x * blockDim.x + threadIdx.x; i < total;
       i += gridDim.x * blockDim.x){
    const int c = (i >> 10) & (CIN - 1);
    float4 zv = ((const float4*)z)[i];
    float4 xv = ((const float4*)x)[i];
    const float m = mean[c], r = rstd[c], ga = gamma[c], be = beta[c];
    float4 o;
    o.x = (zv.x - m) * r * ga + be + xv.x;
    o.y = (zv.y - m) * r * ga + be + xv.y;
    o.z = (zv.z - m) * r * ga + be + xv.z;
    o.w = (zv.w - m) * r * ga + be + xv.w;
    ((float4*)out)[i] = o;
  }
}

// ---------------- launcher --------------------------------------------------
extern "C" void kernel_launch(void* const* d_in, const int* in_sizes, int n_in,
                              void* d_out, int out_size, void* d_ws, size_t ws_size,
                              hipStream_t stream)
{
  const float* x     = (const float*)d_in[0];
  const float* Wt    = (const float*)d_in[1];
  const float* Wp    = (const float*)d_in[2];
  const float* Wg    = (const float*)d_in[3];
  const float* Wz    = (const float*)d_in[4];
  const float* gamma = (const float*)d_in[5];
  const float* beta  = (const float*)d_in[6];
  float* out = (float*)d_out;

  float* wsf = (float*)d_ws;
  size_t off = 0;
  half_t* ST  = (half_t*)(wsf + off); off += (size_t)B_SZ * NN * NN / 2;   // 134MB
  half_t* tTh = (half_t*)(wsf + off); off += (size_t)B_SZ*NN*CP/2;
  half_t* tTl = (half_t*)(wsf + off); off += (size_t)B_SZ*NN*CP/2;
  half_t* pTh = (half_t*)(wsf + off); off += (size_t)B_SZ*NN*CP/2;
  half_t* pTl = (half_t*)(wsf + off); off += (size_t)B_SZ*NN*CP/2;
  half_t* gF  = (half_t*)(wsf + off); off += (size_t)B_SZ*CP*NN/2;
  half_t* xTh = (half_t*)(wsf + off); off += (size_t)B_SZ*NN*CIN/2;
  half_t* xTl = (half_t*)(wsf + off); off += (size_t)B_SZ*NN*CIN/2;
  half_t* Wh  = (half_t*)(wsf + off); off += (size_t)3*CP*CIN/2;
  half_t* Wl  = (half_t*)(wsf + off); off += (size_t)3*CP*CIN/2;
  float*  yp  = wsf + off; off += (size_t)B_SZ * KSL * CP * NN;            // 33.5MB
  float*  pmax= wsf + off; off += (size_t)B_SZ * NT * NN;
  float*  psum= wsf + off; off += (size_t)B_SZ * NT * NN;
  float*  corr= wsf + off; off += (size_t)B_SZ * NT * NN;
  float*  meanb = wsf + off; off += CIN;
  float*  rstdb = wsf + off; off += CIN;
  float*  z = (float*)ST;   // alias: ST dead after y_gemm

  split_w <<<dim3(3, 4),           256, 0, stream>>>(Wt, Wp, Wg, Wh, Wl);
  split_x <<<dim3(64, 4, B_SZ),    256, 0, stream>>>(x, xTh, xTl);
  tpg_gemm<<<dim3(64, 3, B_SZ),    256, 0, stream>>>(Wh, Wl, xTh, xTl,
                                                     tTh, tTl, pTh, pTl, gF);
  s_gemm    <<<dim3(32, 32, B_SZ), 256, 0, stream>>>(tTh, tTl, pTh, pTl,
                                                     ST, pmax, psum);
  merge_corr<<<dim3(16, B_SZ),     256, 0, stream>>>(pmax, psum, corr);
  y_gemm    <<<dim3(64, KSL, B_SZ),256, 0, stream>>>(gF, ST, corr, yp);
  z_gemm    <<<dim3(64, 2, B_SZ),  256, 0, stream>>>(Wz, yp, z);
  bn_stats  <<<dim3(CIN),          256, 0, stream>>>(z, meanb, rstdb);
  finalize_k<<<dim3(2048),         256, 0, stream>>>(z, x, meanb, rstdb,
                                                     gamma, beta, out);
}